// Round 5
// baseline (418.023 us; speedup 1.0000x reference)
//
#include <hip/hip_runtime.h>
#include <math.h>

// STN3d, B=32, C=3, N=4096. Training-mode BN (batch stats), moment-folded.
// kA_xstats: 3x3 second moments of x  -> fold BN1 into W1 (kB)
// kC_gram:   64x64 Gram of h1 (+sum)  -> partials in ws (aliased), kR reduces
// kD_fold2:  var2[o] = w2^T C w2      -> fold BN2 into W2 (W2', b2')
// kE2_layer2: bf16x3 MFMA GEMM 64->128 (h1 built in-kernel, f32->hi/lo LDS),
//             -> relu -> hi/lo split -> h2t planes [b][n][128]
// k5_layer3: bf16x3 MFMA GEMM 128->1024, A read DIRECT from global (no LDS,
//            no barriers in main loop), W3 frags in registers, fused f32 BN3
//            stats + per-(b,o) max/min
// k_fin3_pool + 3x k_fc_bn_relu + k_final.

#define EPS 1e-5f
#define PI_F 3.1415927410125732f

typedef unsigned int u32;
typedef unsigned short u16;
typedef __bf16 bf16x8 __attribute__((ext_vector_type(8)));
typedef float f32x4 __attribute__((ext_vector_type(4)));

__device__ __forceinline__ u16 f2bf(float f) {
  u32 u = __float_as_uint(f);
  return (u16)((u + 0x7FFFu + ((u >> 16) & 1u)) >> 16);
}
__device__ __forceinline__ float bf2f(u16 h) { return __uint_as_float(((u32)h) << 16); }

// ---------------- kA: x second moments (9 sums) -----------------------------------
__global__ __launch_bounds__(256) void kA_xstats(const float* __restrict__ x,
    float* __restrict__ xst) {
  int tg = blockIdx.x * 256 + threadIdx.x;
  int b = tg >> 10, nq = (tg & 1023) << 2;
  const float* xb = x + ((size_t)b * 3) * 4096 + nq;
  float4 a = *(const float4*)(xb);
  float4 c = *(const float4*)(xb + 4096);
  float4 d = *(const float4*)(xb + 8192);
  float p[9];
  p[0] = (a.x + a.y) + (a.z + a.w);
  p[1] = (c.x + c.y) + (c.z + c.w);
  p[2] = (d.x + d.y) + (d.z + d.w);
  p[3] = fmaf(a.x,a.x, fmaf(a.y,a.y, fmaf(a.z,a.z, a.w*a.w)));
  p[4] = fmaf(a.x,c.x, fmaf(a.y,c.y, fmaf(a.z,c.z, a.w*c.w)));
  p[5] = fmaf(a.x,d.x, fmaf(a.y,d.y, fmaf(a.z,d.z, a.w*d.w)));
  p[6] = fmaf(c.x,c.x, fmaf(c.y,c.y, fmaf(c.z,c.z, c.w*c.w)));
  p[7] = fmaf(c.x,d.x, fmaf(c.y,d.y, fmaf(c.z,d.z, c.w*d.w)));
  p[8] = fmaf(d.x,d.x, fmaf(d.y,d.y, fmaf(d.z,d.z, d.w*d.w)));
  #pragma unroll
  for (int k = 0; k < 9; ++k) {
    #pragma unroll
    for (int s = 1; s < 64; s <<= 1) p[k] += __shfl_xor(p[k], s);
  }
  if ((threadIdx.x & 63) == 0) {
    #pragma unroll
    for (int k = 0; k < 9; ++k) atomicAdd(&xst[k], p[k]);
  }
}

// ---------------- kB: fold BN1 into W1 --------------------------------------------
__global__ void kB_fold1(const float* __restrict__ xst,
    const float* __restrict__ w1, const float* __restrict__ b1,
    const float* __restrict__ g1, const float* __restrict__ be1,
    float* __restrict__ w1f, float* __restrict__ b1f) {
  int o = threadIdx.x;
  const float inv = 1.f / 131072.f;
  float mx = xst[0]*inv, my = xst[1]*inv, mz = xst[2]*inv;
  float cxx = xst[3]*inv - mx*mx, cxy = xst[4]*inv - mx*my, cxz = xst[5]*inv - mx*mz;
  float cyy = xst[6]*inv - my*my, cyz = xst[7]*inv - my*mz, czz = xst[8]*inv - mz*mz;
  float wa = w1[o*3], wb = w1[o*3+1], wc = w1[o*3+2];
  float mu = fmaf(wa, mx, fmaf(wb, my, fmaf(wc, mz, b1[o])));
  float var = wa*wa*cxx + wb*wb*cyy + wc*wc*czz
            + 2.f*(wa*wb*cxy + wa*wc*cxz + wb*wc*cyz);
  float s = g1[o] * rsqrtf(var + EPS);
  w1f[o*3]   = s*wa;
  w1f[o*3+1] = s*wb;
  w1f[o*3+2] = s*wc;
  b1f[o] = be1[o] + s*(b1[o] - mu);
}

// ---------------- kC: Gram of h1 (64x64) + column sums ----------------------------
__global__ __launch_bounds__(256) void kC_gram(const float* __restrict__ x,
    const float* __restrict__ w1f, const float* __restrict__ b1f,
    float* __restrict__ gram_part, float* __restrict__ m1v) {
  __shared__ float xs[3][64];
  __shared__ float tile[64][64];
  __shared__ float mred[256];
  int t = threadIdx.x;
  int ch = t & 63;
  float wa = w1f[ch*3], wb = w1f[ch*3+1], wc = w1f[ch*3+2], bf = b1f[ch];
  int ti = t & 7, tj = (t >> 3) & 7, ph = t >> 6;
  int i0 = ti << 3, j0 = tj << 3, p0 = ph << 4;
  float gacc[8][8];
  #pragma unroll
  for (int a = 0; a < 8; ++a)
    #pragma unroll
    for (int c = 0; c < 8; ++c) gacc[a][c] = 0.f;
  float msum = 0.f;
  for (int it = 0; it < 8; ++it) {
    int tile_id = blockIdx.x * 8 + it;
    int bb = tile_id >> 6, n0 = (tile_id & 63) << 6;
    if (t < 192) { int c = t >> 6, n = t & 63; xs[c][n] = x[((size_t)bb*3 + c)*4096 + n0 + n]; }
    __syncthreads();
    #pragma unroll
    for (int r = 0; r < 16; ++r) {
      int pt = (r << 2) | (t >> 6);
      float v = fmaxf(fmaf(wa, xs[0][pt], fmaf(wb, xs[1][pt], fmaf(wc, xs[2][pt], bf))), 0.f);
      tile[pt][ch] = v;
      msum += v;
    }
    __syncthreads();
    #pragma unroll 4
    for (int q = 0; q < 16; ++q) {
      int pt = p0 + q;
      float4 a0 = *(const float4*)(&tile[pt][i0]);
      float4 a1 = *(const float4*)(&tile[pt][i0 + 4]);
      float4 c0 = *(const float4*)(&tile[pt][j0]);
      float4 c1 = *(const float4*)(&tile[pt][j0 + 4]);
      float ai[8] = {a0.x,a0.y,a0.z,a0.w, a1.x,a1.y,a1.z,a1.w};
      float aj[8] = {c0.x,c0.y,c0.z,c0.w, c1.x,c1.y,c1.z,c1.w};
      #pragma unroll
      for (int a = 0; a < 8; ++a)
        #pragma unroll
        for (int c = 0; c < 8; ++c) gacc[a][c] = fmaf(ai[a], aj[c], gacc[a][c]);
    }
    __syncthreads();
  }
  mred[t] = msum;
  __syncthreads();
  if (t < 64) atomicAdd(&m1v[t], mred[t] + mred[t+64] + mred[t+128] + mred[t+192]);
  float* gl = &tile[0][0];
  if (ph == 0) {
    #pragma unroll
    for (int a = 0; a < 8; ++a)
      #pragma unroll
      for (int c = 0; c < 8; ++c) gl[(i0+a)*64 + j0 + c] = gacc[a][c];
  }
  __syncthreads();
  #pragma unroll
  for (int p = 1; p < 4; ++p) {
    if (ph == p) {
      #pragma unroll
      for (int a = 0; a < 8; ++a)
        #pragma unroll
        for (int c = 0; c < 8; ++c) gl[(i0+a)*64 + j0 + c] += gacc[a][c];
    }
    __syncthreads();
  }
  float* gp = gram_part + (size_t)blockIdx.x * 4096;
  #pragma unroll
  for (int r = 0; r < 16; ++r) gp[r*256 + t] = gl[r*256 + t];
}

// ---------------- kR: reduce gram partials ----------------------------------------
__global__ __launch_bounds__(256) void kR_gramred(const float* __restrict__ gram_part,
    float* __restrict__ gram) {
  int cell = blockIdx.x * 256 + threadIdx.x;
  float s = 0.f;
  for (int blk = 0; blk < 256; ++blk) s += gram_part[(size_t)blk*4096 + cell];
  gram[cell] = s;
}

// ---------------- kD: fold BN2 into W2 --------------------------------------------
__global__ void kD_fold2(const float* __restrict__ gram, const float* __restrict__ m1v,
    const float* __restrict__ w2, const float* __restrict__ b2,
    const float* __restrict__ g2, const float* __restrict__ be2,
    float* __restrict__ w2f, float* __restrict__ b2f) {
  __shared__ float wrow[64];
  int o = blockIdx.x, i = threadIdx.x;
  wrow[i] = w2[o*64 + i];
  __syncthreads();
  const float inv = 1.f / 131072.f;
  float si = 0.f;
  #pragma unroll 8
  for (int j = 0; j < 64; ++j) si = fmaf(wrow[j], gram[j*64 + i], si);
  float qi = wrow[i] * si;
  float di = wrow[i] * (m1v[i] * inv);
  #pragma unroll
  for (int d2 = 1; d2 < 64; d2 <<= 1) { qi += __shfl_xor(qi, d2); di += __shfl_xor(di, d2); }
  float mu2 = di + b2[o];
  float var = qi*inv - di*di;
  float s = g2[o] * rsqrtf(var + EPS);
  w2f[o*64 + i] = s * wrow[i];
  if (i == 0) b2f[o] = be2[o] + s*(b2[o] - mu2);
}

// ---------------- kE2: layer2 via bf16x3 MFMA -> relu -> hi/lo -> h2t -------------
// 256 blocks (b, 512-n tile), 256 thr = 4 waves (2 wo x 2 wn).
__global__ __launch_bounds__(256) void kE2_layer2(const float* __restrict__ x,
    const float* __restrict__ w1f, const float* __restrict__ b1f,
    const float* __restrict__ w2f, const float* __restrict__ b2f,
    u16* __restrict__ h2t_hi, u16* __restrict__ h2t_lo) {
  __shared__ float xs[3][512];
  __shared__ float4 w1s4[64];                 // (w0,w1,w2,bias)
  __shared__ __align__(16) u16 h1h[128][64];  // XOR-swizzled rows
  __shared__ __align__(16) u16 h1l[128][64];
  int t = threadIdx.x;
  int b = blockIdx.x >> 3;
  int ntile = (blockIdx.x & 7) << 9;
  int lane = t & 63, wid = t >> 6;
  int wo = wid & 1, wn = wid >> 1;
  #pragma unroll
  for (int i = 0; i < 6; ++i) {
    int idx = (i << 8) | t;
    int c = idx >> 9, n = idx & 511;
    xs[c][n] = x[((size_t)b*3 + c)*4096 + ntile + n];
  }
  if (t < 64) w1s4[t] = make_float4(w1f[t*3], w1f[t*3+1], w1f[t*3+2], b1f[t]);
  // W2' frags (o = wo*64 + of*16 + lane&15, k = ks*32 + (lane>>4)*8)
  bf16x8 wf_hi[2][4], wf_lo[2][4];
  float bv[4];
  #pragma unroll
  for (int of = 0; of < 4; ++of) {
    int o = (wo << 6) | (of << 4) | (lane & 15);
    bv[of] = b2f[o];
    #pragma unroll
    for (int ks = 0; ks < 2; ++ks) {
      const float* src = w2f + o*64 + (ks << 5) + ((lane >> 4) << 3);
      float4 f0 = *(const float4*)src;
      float4 f1 = *(const float4*)(src + 4);
      float fv[8] = {f0.x,f0.y,f0.z,f0.w, f1.x,f1.y,f1.z,f1.w};
      u32 hw[4], lw[4];
      #pragma unroll
      for (int p2 = 0; p2 < 4; ++p2) {
        u16 h0 = f2bf(fv[2*p2]), h1 = f2bf(fv[2*p2+1]);
        u16 l0 = f2bf(fv[2*p2] - bf2f(h0)), l1 = f2bf(fv[2*p2+1] - bf2f(h1));
        hw[p2] = (u32)h0 | ((u32)h1 << 16);
        lw[p2] = (u32)l0 | ((u32)l1 << 16);
      }
      uint4 H = make_uint4(hw[0],hw[1],hw[2],hw[3]);
      uint4 L = make_uint4(lw[0],lw[1],lw[2],lw[3]);
      wf_hi[ks][of] = *(const bf16x8*)&H;
      wf_lo[ks][of] = *(const bf16x8*)&L;
    }
  }
  __syncthreads();
  const f32x4 zero4 = {0.f,0.f,0.f,0.f};
  for (int chunk = 0; chunk < 4; ++chunk) {
    {   // h1 for 128 n: thread = (n = t>>1, k-half = t&1)
      int n = t >> 1;
      int kb = (t & 1) << 5;
      int nL = (chunk << 7) | n;
      float xa = xs[0][nL], xb = xs[1][nL], xc = xs[2][nL];
      char* rowh = (char*)&h1h[0][0] + (n << 7);
      char* rowl = (char*)&h1l[0][0] + (n << 7);
      int sw = (n & 7) << 4;
      #pragma unroll
      for (int kk = 0; kk < 32; kk += 2) {
        float4 wv0 = w1s4[kb + kk];
        float4 wv1 = w1s4[kb + kk + 1];
        float v0 = fmaxf(fmaf(wv0.x, xa, fmaf(wv0.y, xb, fmaf(wv0.z, xc, wv0.w))), 0.f);
        float v1 = fmaxf(fmaf(wv1.x, xa, fmaf(wv1.y, xb, fmaf(wv1.z, xc, wv1.w))), 0.f);
        u16 h0 = f2bf(v0), h1_ = f2bf(v1);
        u32 hw = (u32)h0 | ((u32)h1_ << 16);
        u32 lw = (u32)f2bf(v0 - bf2f(h0)) | ((u32)f2bf(v1 - bf2f(h1_)) << 16);
        int byte = ((kb + kk) << 1) ^ sw;
        *(u32*)(rowh + byte) = hw;
        *(u32*)(rowl + byte) = lw;
      }
    }
    __syncthreads();
    #pragma unroll
    for (int p = 0; p < 4; ++p) {
      int nrel = (wn << 6) | (p << 4) | (lane & 15);
      int abyte = (nrel << 7) | ((lane >> 4) << 4);
      int asw = (nrel & 7) << 4;
      f32x4 acc[4] = {zero4, zero4, zero4, zero4};
      #pragma unroll
      for (int ks = 0; ks < 2; ++ks) {
        int ad = (abyte | (ks << 6)) ^ asw;
        bf16x8 ah = *(const bf16x8*)((const char*)&h1h[0][0] + ad);
        bf16x8 al = *(const bf16x8*)((const char*)&h1l[0][0] + ad);
        #pragma unroll
        for (int of = 0; of < 4; ++of) {
          acc[of] = __builtin_amdgcn_mfma_f32_16x16x32_bf16(al, wf_hi[ks][of], acc[of], 0, 0, 0);
          acc[of] = __builtin_amdgcn_mfma_f32_16x16x32_bf16(ah, wf_lo[ks][of], acc[of], 0, 0, 0);
          acc[of] = __builtin_amdgcn_mfma_f32_16x16x32_bf16(ah, wf_hi[ks][of], acc[of], 0, 0, 0);
        }
      }
      int nbase = ntile | (chunk << 7) | (wn << 6) | (p << 4) | ((lane >> 4) << 2);
      #pragma unroll
      for (int of = 0; of < 4; ++of) {
        int o = (wo << 6) | (of << 4) | (lane & 15);
        #pragma unroll
        for (int r = 0; r < 4; ++r) {
          float v = fmaxf(acc[of][r] + bv[of], 0.f);
          u16 h = f2bf(v);
          u16 l = f2bf(v - bf2f(h));
          size_t gi = (((size_t)(b << 12) | (nbase + r)) << 7) | o;
          h2t_hi[gi] = h;
          h2t_lo[gi] = l;
        }
      }
    }
    __syncthreads();
  }
}

// ---------------- k5: bf16x3 MFMA 128->1024, A direct from global, no barriers ----
// grid 1024 = 32b x 16 otile(64-o) x 2 half(2048-n); 256 thr (2 wo x 2 wn).
__global__ __launch_bounds__(256, 3) void k5_layer3(
    const u16* __restrict__ h2t_hi, const u16* __restrict__ h2t_lo,
    const float* __restrict__ w3,
    float* __restrict__ sum3, float* __restrict__ sq3,
    float* __restrict__ maxv, float* __restrict__ minv) {
  __shared__ float part[2][64][4];
  int t = threadIdx.x, lane = t & 63, wid = t >> 6;
  int wo = wid & 1, wn = wid >> 1;
  int id = blockIdx.x;
  int xcd = id & 7, idx = id >> 3;
  int b = (xcd << 2) | (idx >> 5);      // consecutive ids on an XCD share b
  int sub = idx & 31;
  int otile = sub >> 1, half = sub & 1;
  // W3 frags -> registers (hi/lo): o = otile*64 + wo*32 + of*16 + lane&15
  bf16x8 wf_hi[4][2], wf_lo[4][2];
  #pragma unroll
  for (int of = 0; of < 2; ++of) {
    int o = (otile << 6) | (wo << 5) | (of << 4) | (lane & 15);
    #pragma unroll
    for (int ks = 0; ks < 4; ++ks) {
      const float* src = w3 + (size_t)o*128 + (ks << 5) + ((lane >> 4) << 3);
      float4 f0 = *(const float4*)src;
      float4 f1 = *(const float4*)(src + 4);
      float fv[8] = {f0.x,f0.y,f0.z,f0.w, f1.x,f1.y,f1.z,f1.w};
      u32 hw[4], lw[4];
      #pragma unroll
      for (int p2 = 0; p2 < 4; ++p2) {
        u16 h0 = f2bf(fv[2*p2]), h1 = f2bf(fv[2*p2+1]);
        u16 l0 = f2bf(fv[2*p2] - bf2f(h0)), l1 = f2bf(fv[2*p2+1] - bf2f(h1));
        hw[p2] = (u32)h0 | ((u32)h1 << 16);
        lw[p2] = (u32)l0 | ((u32)l1 << 16);
      }
      uint4 H = make_uint4(hw[0],hw[1],hw[2],hw[3]);
      uint4 L = make_uint4(lw[0],lw[1],lw[2],lw[3]);
      wf_hi[ks][of] = *(const bf16x8*)&H;
      wf_lo[ks][of] = *(const bf16x8*)&L;
    }
  }
  // A pointers: n = half*2048 + p*32 + wn*16 + lane&15 ; k = ks*32 + (lane>>4)*8
  int nstart = (half << 11) | (wn << 4) | (lane & 15);
  const u16* ph = h2t_hi + ((((size_t)b << 12) | nstart) << 7) + ((lane >> 4) << 3);
  const u16* pl = h2t_lo + ((((size_t)b << 12) | nstart) << 7) + ((lane >> 4) << 3);
  float rs[2] = {0.f,0.f};
  float rq[2] = {0.f,0.f};
  float rmx[2] = {-3.4e38f,-3.4e38f};
  float rmn[2] = { 3.4e38f, 3.4e38f};
  const f32x4 zero4 = {0.f,0.f,0.f,0.f};
  #pragma unroll 2
  for (int p = 0; p < 64; ++p) {
    const u16* rh = ph + (p << 12);     // 32 rows x 128 elems
    const u16* rl = pl + (p << 12);
    bf16x8 ah[4], al[4];
    #pragma unroll
    for (int ks = 0; ks < 4; ++ks) {
      ah[ks] = *(const bf16x8*)(rh + (ks << 5));
      al[ks] = *(const bf16x8*)(rl + (ks << 5));
    }
    f32x4 a0 = zero4, a1 = zero4;
    #pragma unroll
    for (int ks = 0; ks < 4; ++ks) {
      a0 = __builtin_amdgcn_mfma_f32_16x16x32_bf16(al[ks], wf_hi[ks][0], a0, 0, 0, 0);
      a0 = __builtin_amdgcn_mfma_f32_16x16x32_bf16(ah[ks], wf_lo[ks][0], a0, 0, 0, 0);
      a0 = __builtin_amdgcn_mfma_f32_16x16x32_bf16(ah[ks], wf_hi[ks][0], a0, 0, 0, 0);
      a1 = __builtin_amdgcn_mfma_f32_16x16x32_bf16(al[ks], wf_hi[ks][1], a1, 0, 0, 0);
      a1 = __builtin_amdgcn_mfma_f32_16x16x32_bf16(ah[ks], wf_lo[ks][1], a1, 0, 0, 0);
      a1 = __builtin_amdgcn_mfma_f32_16x16x32_bf16(ah[ks], wf_hi[ks][1], a1, 0, 0, 0);
    }
    rs[0] += (a0[0] + a0[1]) + (a0[2] + a0[3]);
    rq[0] = fmaf(a0[0],a0[0], fmaf(a0[1],a0[1], fmaf(a0[2],a0[2], fmaf(a0[3],a0[3], rq[0]))));
    rmx[0] = fmaxf(rmx[0], fmaxf(fmaxf(a0[0],a0[1]), fmaxf(a0[2],a0[3])));
    rmn[0] = fminf(rmn[0], fminf(fminf(a0[0],a0[1]), fminf(a0[2],a0[3])));
    rs[1] += (a1[0] + a1[1]) + (a1[2] + a1[3]);
    rq[1] = fmaf(a1[0],a1[0], fmaf(a1[1],a1[1], fmaf(a1[2],a1[2], fmaf(a1[3],a1[3], rq[1]))));
    rmx[1] = fmaxf(rmx[1], fmaxf(fmaxf(a1[0],a1[1]), fmaxf(a1[2],a1[3])));
    rmn[1] = fminf(rmn[1], fminf(fminf(a1[0],a1[1]), fminf(a1[2],a1[3])));
  }
  // cross-lane (o = lane&15 preserved)
  #pragma unroll
  for (int of = 0; of < 2; ++of) {
    rs[of] += __shfl_xor(rs[of], 16); rs[of] += __shfl_xor(rs[of], 32);
    rq[of] += __shfl_xor(rq[of], 16); rq[of] += __shfl_xor(rq[of], 32);
    rmx[of] = fmaxf(rmx[of], __shfl_xor(rmx[of], 16)); rmx[of] = fmaxf(rmx[of], __shfl_xor(rmx[of], 32));
    rmn[of] = fminf(rmn[of], __shfl_xor(rmn[of], 16)); rmn[of] = fminf(rmn[of], __shfl_xor(rmn[of], 32));
  }
  if (lane < 16) {
    #pragma unroll
    for (int of = 0; of < 2; ++of) {
      int ol = (wo << 5) | (of << 4) | lane;
      part[wn][ol][0] = rs[of];
      part[wn][ol][1] = rq[of];
      part[wn][ol][2] = rmx[of];
      part[wn][ol][3] = rmn[of];
    }
  }
  __syncthreads();
  if (t < 64) {
    float S = part[0][t][0] + part[1][t][0];
    float Q = part[0][t][1] + part[1][t][1];
    float MX = fmaxf(part[0][t][2], part[1][t][2]);
    float MN = fminf(part[0][t][3], part[1][t][3]);
    int go = (((half << 5) | b) << 10) | (otile << 6) | t;
    sum3[go] = S; sq3[go] = Q; maxv[go] = MX; minv[go] = MN;
  }
}

// ---------------- finalize stats3 (+bias fold) + pooled ---------------------------
__global__ void k_fin3_pool(const float* __restrict__ sum3, const float* __restrict__ sq3,
    const float* __restrict__ maxv, const float* __restrict__ minv,
    const float* __restrict__ b3,
    const float* __restrict__ g, const float* __restrict__ be, float* __restrict__ pool) {
  int o = blockIdx.x*256 + threadIdx.x;
  float S = 0.f, Q = 0.f;
  for (int h = 0; h < 2; ++h)
    for (int b = 0; b < 32; ++b) { int gi = (((h<<5)|b)<<10) | o; S += sum3[gi]; Q += sq3[gi]; }
  const float inv = 1.f/131072.f;
  float ma = S*inv;
  float m = ma + b3[o];
  float var = Q*inv - ma*ma;
  float sc = g[o]*rsqrtf(var + EPS);
  float sh = be[o] - sc*m;
  bool pos = (sc >= 0.f);
  for (int b = 0; b < 32; ++b) {
    int g0 = (b << 10) | o, g1 = ((32 + b) << 10) | o;
    float v = pos ? fmaxf(maxv[g0], maxv[g1]) : fminf(minv[g0], minv[g1]);
    pool[(b << 10) | o] = fmaxf(fmaf(sc, v + b3[o], sh), 0.f);
  }
}

// ---------------- fused FC + batch-BN + ReLU --------------------------------------
__global__ __launch_bounds__(256) void k_fc_bn_relu(const float* __restrict__ in,
    const float* __restrict__ w, const float* __restrict__ fb,
    const float* __restrict__ g, const float* __restrict__ be,
    float* __restrict__ out, int K, int F) {
  __shared__ float wrow[1024];
  __shared__ float preb[32];
  int o = blockIdx.x, t = threadIdx.x;
  for (int k = t; k < K; k += 256) wrow[k] = w[(size_t)o*K + k];
  __syncthreads();
  int b = t >> 3, j = t & 7;
  int per = K >> 3;
  const float* inb = in + (size_t)b*K + j*per;
  const float* wp  = wrow + j*per;
  float p = 0.f;
  for (int k = 0; k < per; ++k) p = fmaf(inb[k], wp[k], p);
  p += __shfl_xor(p, 1); p += __shfl_xor(p, 2); p += __shfl_xor(p, 4);
  if (j == 0) preb[b] = p + fb[o];
  __syncthreads();
  if (t < 32) {
    float v = preb[t];
    float s = v;
    #pragma unroll
    for (int d = 1; d < 32; d <<= 1) s += __shfl_xor(s, d);
    float m = s * 0.03125f;
    float dv = v - m;
    float q = dv*dv;
    #pragma unroll
    for (int d = 1; d < 32; d <<= 1) q += __shfl_xor(q, d);
    float var = q * 0.03125f;
    float sc = g[o]*rsqrtf(var + EPS);
    out[(size_t)t*F + o] = fmaxf(fmaf(sc, dv, be[o]), 0.f);
  }
}

// ---------------- angles + Euler->rotation ----------------------------------------
__global__ __launch_bounds__(128) void k_final(const float* __restrict__ h6,
    const float* __restrict__ fw4, const float* __restrict__ fb4, float* __restrict__ out) {
  __shared__ float angs[32][3];
  int t = threadIdx.x;
  if (t < 96) {
    int b = t / 3, j = t % 3;
    float p = 0.f;
    #pragma unroll 4
    for (int k = 0; k < 128; ++k) p = fmaf(h6[b*128+k], fw4[j*128+k], p);
    angs[b][j] = (p + fb4[j]) * PI_F;
  }
  __syncthreads();
  if (t < 32) {
    float a = angs[t][0], bb = angs[t][1], c = angs[t][2];
    float sa, ca; sincosf(a,  &sa, &ca);
    float sb, cb; sincosf(bb, &sb, &cb);
    float sc, cc; sincosf(c,  &sc, &cc);
    float* o9 = out + t*9;
    o9[0] = cc*cb;
    o9[1] = fmaf(cc*sb, sa, -sc*ca);
    o9[2] = fmaf(cc*sb, ca,  sc*sa);
    o9[3] = sc*cb;
    o9[4] = fmaf(sc*sb, sa,  cc*ca);
    o9[5] = fmaf(sc*sb, ca, -cc*sa);
    o9[6] = -sb;
    o9[7] = cb*sa;
    o9[8] = cb*ca;
  }
}

extern "C" void kernel_launch(void* const* d_in, const int* in_sizes, int n_in,
                              void* d_out, int out_size, void* d_ws, size_t ws_size,
                              hipStream_t stream) {
  (void)in_sizes; (void)n_in; (void)out_size; (void)ws_size;
  const float* x   = (const float*)d_in[0];
  const float* w1  = (const float*)d_in[1];
  const float* b1  = (const float*)d_in[2];
  const float* g1  = (const float*)d_in[3];
  const float* be1 = (const float*)d_in[4];
  const float* w2  = (const float*)d_in[5];
  const float* b2  = (const float*)d_in[6];
  const float* g2  = (const float*)d_in[7];
  const float* be2 = (const float*)d_in[8];
  const float* w3  = (const float*)d_in[9];
  const float* b3  = (const float*)d_in[10];
  const float* g3  = (const float*)d_in[11];
  const float* be3 = (const float*)d_in[12];
  const float* fw1 = (const float*)d_in[13];
  const float* fb1 = (const float*)d_in[14];
  const float* g4  = (const float*)d_in[15];
  const float* be4 = (const float*)d_in[16];
  const float* fw2 = (const float*)d_in[17];
  const float* fb2 = (const float*)d_in[18];
  const float* g5p = (const float*)d_in[19];
  const float* be5 = (const float*)d_in[20];
  const float* fw3 = (const float*)d_in[21];
  const float* fb3 = (const float*)d_in[22];
  const float* g6  = (const float*)d_in[23];
  const float* be6 = (const float*)d_in[24];
  const float* fw4 = (const float*)d_in[25];
  const float* fb4 = (const float*)d_in[26];

  u16* h2t_hi = (u16*)d_ws;                     // 32 MiB
  u16* h2t_lo = (u16*)d_ws + 16777216;          // 32 MiB
  float* gram_part = (float*)d_ws;              // 4 MiB, aliases h2t (pre-kE2 only)
  float* acc0 = (float*)d_ws + 16777216;
  float* xst  = acc0;                           // 16
  float* m1v  = acc0 + 16;                      // 64
  float* gram = acc0 + 80;                      // 4096
  float* w1f  = acc0 + 4176;                    // 192
  float* b1f  = acc0 + 4368;                    // 64
  float* w2f  = acc0 + 4432;                    // 8192
  float* b2f  = acc0 + 12624;                   // 128
  float* sum3 = acc0 + 12752;                   // 2*32*1024
  float* sq3  = acc0 + 78288;
  float* maxv = acc0 + 143824;
  float* minv = acc0 + 209360;
  float* pool = acc0 + 274896;                  // 32768
  float* h4v  = acc0 + 307664;                  // 16384
  float* h5v  = acc0 + 324048;                  // 8192
  float* h6v  = acc0 + 332240;                  // 4096

  hipMemsetAsync(acc0, 0, 80ull*4, stream);     // xst + m1v

  kA_xstats<<<128, 256, 0, stream>>>(x, xst);
  kB_fold1<<<1, 64, 0, stream>>>(xst, w1, b1, g1, be1, w1f, b1f);
  kC_gram<<<256, 256, 0, stream>>>(x, w1f, b1f, gram_part, m1v);
  kR_gramred<<<16, 256, 0, stream>>>(gram_part, gram);
  kD_fold2<<<128, 64, 0, stream>>>(gram, m1v, w2, b2, g2, be2, w2f, b2f);
  kE2_layer2<<<256, 256, 0, stream>>>(x, w1f, b1f, w2f, b2f, h2t_hi, h2t_lo);
  k5_layer3<<<1024, 256, 0, stream>>>(h2t_hi, h2t_lo, w3, sum3, sq3, maxv, minv);
  k_fin3_pool<<<4, 256, 0, stream>>>(sum3, sq3, maxv, minv, b3, g3, be3, pool);
  k_fc_bn_relu<<<512, 256, 0, stream>>>(pool, fw1, fb1, g4, be4, h4v, 1024, 512);
  k_fc_bn_relu<<<256, 256, 0, stream>>>(h4v, fw2, fb2, g5p, be5, h5v, 512, 256);
  k_fc_bn_relu<<<128, 256, 0, stream>>>(h5v, fw3, fb3, g6, be6, h6v, 256, 128);
  k_final<<<1, 128, 0, stream>>>(h6v, fw4, fb4, (float*)d_out);
}

// Round 6
// 272.646 us; speedup vs baseline: 1.5332x; 1.5332x over previous
//
#include <hip/hip_runtime.h>
#include <math.h>

// STN3d, B=32, C=3, N=4096. Training-mode BN (batch stats), moment-folded.
// kA_xstats -> kB_fold1 -> kC_gram -> kR -> kD_fold2 -> kE2_layer2 (MFMA) ->
// k5_layer3 (MFMA, 4-deep counted-vmcnt pipeline, pipelined stats) ->
// k_fin3_pool -> 3x k_fc_bn_relu -> k_final.

#define EPS 1e-5f
#define PI_F 3.1415927410125732f

typedef unsigned int u32;
typedef unsigned short u16;
typedef __bf16 bf16x8 __attribute__((ext_vector_type(8)));
typedef float f32x4 __attribute__((ext_vector_type(4)));

__device__ __forceinline__ u16 f2bf(float f) {
  u32 u = __float_as_uint(f);
  return (u16)((u + 0x7FFFu + ((u >> 16) & 1u)) >> 16);
}
__device__ __forceinline__ float bf2f(u16 h) { return __uint_as_float(((u32)h) << 16); }

// ---------------- kA: x second moments (9 sums) -----------------------------------
__global__ __launch_bounds__(256) void kA_xstats(const float* __restrict__ x,
    float* __restrict__ xst) {
  int tg = blockIdx.x * 256 + threadIdx.x;
  int b = tg >> 10, nq = (tg & 1023) << 2;
  const float* xb = x + ((size_t)b * 3) * 4096 + nq;
  float4 a = *(const float4*)(xb);
  float4 c = *(const float4*)(xb + 4096);
  float4 d = *(const float4*)(xb + 8192);
  float p[9];
  p[0] = (a.x + a.y) + (a.z + a.w);
  p[1] = (c.x + c.y) + (c.z + c.w);
  p[2] = (d.x + d.y) + (d.z + d.w);
  p[3] = fmaf(a.x,a.x, fmaf(a.y,a.y, fmaf(a.z,a.z, a.w*a.w)));
  p[4] = fmaf(a.x,c.x, fmaf(a.y,c.y, fmaf(a.z,c.z, a.w*c.w)));
  p[5] = fmaf(a.x,d.x, fmaf(a.y,d.y, fmaf(a.z,d.z, a.w*d.w)));
  p[6] = fmaf(c.x,c.x, fmaf(c.y,c.y, fmaf(c.z,c.z, c.w*c.w)));
  p[7] = fmaf(c.x,d.x, fmaf(c.y,d.y, fmaf(c.z,d.z, c.w*d.w)));
  p[8] = fmaf(d.x,d.x, fmaf(d.y,d.y, fmaf(d.z,d.z, d.w*d.w)));
  #pragma unroll
  for (int k = 0; k < 9; ++k) {
    #pragma unroll
    for (int s = 1; s < 64; s <<= 1) p[k] += __shfl_xor(p[k], s);
  }
  if ((threadIdx.x & 63) == 0) {
    #pragma unroll
    for (int k = 0; k < 9; ++k) atomicAdd(&xst[k], p[k]);
  }
}

// ---------------- kB: fold BN1 into W1 --------------------------------------------
__global__ void kB_fold1(const float* __restrict__ xst,
    const float* __restrict__ w1, const float* __restrict__ b1,
    const float* __restrict__ g1, const float* __restrict__ be1,
    float* __restrict__ w1f, float* __restrict__ b1f) {
  int o = threadIdx.x;
  const float inv = 1.f / 131072.f;
  float mx = xst[0]*inv, my = xst[1]*inv, mz = xst[2]*inv;
  float cxx = xst[3]*inv - mx*mx, cxy = xst[4]*inv - mx*my, cxz = xst[5]*inv - mx*mz;
  float cyy = xst[6]*inv - my*my, cyz = xst[7]*inv - my*mz, czz = xst[8]*inv - mz*mz;
  float wa = w1[o*3], wb = w1[o*3+1], wc = w1[o*3+2];
  float mu = fmaf(wa, mx, fmaf(wb, my, fmaf(wc, mz, b1[o])));
  float var = wa*wa*cxx + wb*wb*cyy + wc*wc*czz
            + 2.f*(wa*wb*cxy + wa*wc*cxz + wb*wc*cyz);
  float s = g1[o] * rsqrtf(var + EPS);
  w1f[o*3]   = s*wa;
  w1f[o*3+1] = s*wb;
  w1f[o*3+2] = s*wc;
  b1f[o] = be1[o] + s*(b1[o] - mu);
}

// ---------------- kC: Gram of h1 (64x64) + column sums ----------------------------
// 512 blocks x 256 thr; each block: 4 tiles of 64 points.
__global__ __launch_bounds__(256) void kC_gram(const float* __restrict__ x,
    const float* __restrict__ w1f, const float* __restrict__ b1f,
    float* __restrict__ gram_part, float* __restrict__ m1v) {
  __shared__ float xs[3][64];
  __shared__ float tile[64][64];
  __shared__ float mred[256];
  int t = threadIdx.x;
  int ch = t & 63;
  float wa = w1f[ch*3], wb = w1f[ch*3+1], wc = w1f[ch*3+2], bf = b1f[ch];
  int ti = t & 7, tj = (t >> 3) & 7, ph = t >> 6;
  int i0 = ti << 3, j0 = tj << 3, p0 = ph << 4;
  float gacc[8][8];
  #pragma unroll
  for (int a = 0; a < 8; ++a)
    #pragma unroll
    for (int c = 0; c < 8; ++c) gacc[a][c] = 0.f;
  float msum = 0.f;
  for (int it = 0; it < 4; ++it) {
    int tile_id = blockIdx.x * 4 + it;
    int bb = tile_id >> 6, n0 = (tile_id & 63) << 6;
    if (t < 192) { int c = t >> 6, n = t & 63; xs[c][n] = x[((size_t)bb*3 + c)*4096 + n0 + n]; }
    __syncthreads();
    #pragma unroll
    for (int r = 0; r < 16; ++r) {
      int pt = (r << 2) | (t >> 6);
      float v = fmaxf(fmaf(wa, xs[0][pt], fmaf(wb, xs[1][pt], fmaf(wc, xs[2][pt], bf))), 0.f);
      tile[pt][ch] = v;
      msum += v;
    }
    __syncthreads();
    #pragma unroll 4
    for (int q = 0; q < 16; ++q) {
      int pt = p0 + q;
      float4 a0 = *(const float4*)(&tile[pt][i0]);
      float4 a1 = *(const float4*)(&tile[pt][i0 + 4]);
      float4 c0 = *(const float4*)(&tile[pt][j0]);
      float4 c1 = *(const float4*)(&tile[pt][j0 + 4]);
      float ai[8] = {a0.x,a0.y,a0.z,a0.w, a1.x,a1.y,a1.z,a1.w};
      float aj[8] = {c0.x,c0.y,c0.z,c0.w, c1.x,c1.y,c1.z,c1.w};
      #pragma unroll
      for (int a = 0; a < 8; ++a)
        #pragma unroll
        for (int c = 0; c < 8; ++c) gacc[a][c] = fmaf(ai[a], aj[c], gacc[a][c]);
    }
    __syncthreads();
  }
  mred[t] = msum;
  __syncthreads();
  if (t < 64) atomicAdd(&m1v[t], mred[t] + mred[t+64] + mred[t+128] + mred[t+192]);
  float* gl = &tile[0][0];
  if (ph == 0) {
    #pragma unroll
    for (int a = 0; a < 8; ++a)
      #pragma unroll
      for (int c = 0; c < 8; ++c) gl[(i0+a)*64 + j0 + c] = gacc[a][c];
  }
  __syncthreads();
  #pragma unroll
  for (int p = 1; p < 4; ++p) {
    if (ph == p) {
      #pragma unroll
      for (int a = 0; a < 8; ++a)
        #pragma unroll
        for (int c = 0; c < 8; ++c) gl[(i0+a)*64 + j0 + c] += gacc[a][c];
    }
    __syncthreads();
  }
  float* gp = gram_part + (size_t)blockIdx.x * 4096;
  #pragma unroll
  for (int r = 0; r < 16; ++r) gp[r*256 + t] = gl[r*256 + t];
}

// ---------------- kR: reduce gram partials ----------------------------------------
__global__ __launch_bounds__(256) void kR_gramred(const float* __restrict__ gram_part,
    float* __restrict__ gram) {
  int cell = blockIdx.x * 256 + threadIdx.x;
  float s = 0.f;
  for (int blk = 0; blk < 512; ++blk) s += gram_part[(size_t)blk*4096 + cell];
  gram[cell] = s;
}

// ---------------- kD: fold BN2 into W2 --------------------------------------------
__global__ void kD_fold2(const float* __restrict__ gram, const float* __restrict__ m1v,
    const float* __restrict__ w2, const float* __restrict__ b2,
    const float* __restrict__ g2, const float* __restrict__ be2,
    float* __restrict__ w2f, float* __restrict__ b2f) {
  __shared__ float wrow[64];
  int o = blockIdx.x, i = threadIdx.x;
  wrow[i] = w2[o*64 + i];
  __syncthreads();
  const float inv = 1.f / 131072.f;
  float si = 0.f;
  #pragma unroll 8
  for (int j = 0; j < 64; ++j) si = fmaf(wrow[j], gram[j*64 + i], si);
  float qi = wrow[i] * si;
  float di = wrow[i] * (m1v[i] * inv);
  #pragma unroll
  for (int d2 = 1; d2 < 64; d2 <<= 1) { qi += __shfl_xor(qi, d2); di += __shfl_xor(di, d2); }
  float mu2 = di + b2[o];
  float var = qi*inv - di*di;
  float s = g2[o] * rsqrtf(var + EPS);
  w2f[o*64 + i] = s * wrow[i];
  if (i == 0) b2f[o] = be2[o] + s*(b2[o] - mu2);
}

// ---------------- kE2: layer2 via bf16x3 MFMA -> relu -> hi/lo -> h2t -------------
// 512 blocks (b x 16 n-tiles of 256), 256 thr = 4 waves (2 wo x 2 wn).
__global__ __launch_bounds__(256) void kE2_layer2(const float* __restrict__ x,
    const float* __restrict__ w1f, const float* __restrict__ b1f,
    const float* __restrict__ w2f, const float* __restrict__ b2f,
    u16* __restrict__ h2t_hi, u16* __restrict__ h2t_lo) {
  __shared__ float xs[3][256];
  __shared__ float4 w1s4[64];
  __shared__ __align__(16) u16 h1h[128][64];
  __shared__ __align__(16) u16 h1l[128][64];
  int t = threadIdx.x;
  int b = ((blockIdx.x & 7) << 2) | ((blockIdx.x >> 3) & 3);   // XCD-aligned with k5
  int ntile = (blockIdx.x >> 5) << 8;
  int lane = t & 63, wid = t >> 6;
  int wo = wid & 1, wn = wid >> 1;
  #pragma unroll
  for (int i = 0; i < 3; ++i) {
    int idx = (i << 8) | t;
    int c = idx >> 8, n = idx & 255;
    xs[c][n] = x[((size_t)b*3 + c)*4096 + ntile + n];
  }
  if (t < 64) w1s4[t] = make_float4(w1f[t*3], w1f[t*3+1], w1f[t*3+2], b1f[t]);
  bf16x8 wf_hi[2][4], wf_lo[2][4];
  float bv[4];
  #pragma unroll
  for (int of = 0; of < 4; ++of) {
    int o = (wo << 6) | (of << 4) | (lane & 15);
    bv[of] = b2f[o];
    #pragma unroll
    for (int ks = 0; ks < 2; ++ks) {
      const float* src = w2f + o*64 + (ks << 5) + ((lane >> 4) << 3);
      float4 f0 = *(const float4*)src;
      float4 f1 = *(const float4*)(src + 4);
      float fv[8] = {f0.x,f0.y,f0.z,f0.w, f1.x,f1.y,f1.z,f1.w};
      u32 hw[4], lw[4];
      #pragma unroll
      for (int p2 = 0; p2 < 4; ++p2) {
        u16 h0 = f2bf(fv[2*p2]), h1 = f2bf(fv[2*p2+1]);
        u16 l0 = f2bf(fv[2*p2] - bf2f(h0)), l1 = f2bf(fv[2*p2+1] - bf2f(h1));
        hw[p2] = (u32)h0 | ((u32)h1 << 16);
        lw[p2] = (u32)l0 | ((u32)l1 << 16);
      }
      uint4 H = make_uint4(hw[0],hw[1],hw[2],hw[3]);
      uint4 L = make_uint4(lw[0],lw[1],lw[2],lw[3]);
      wf_hi[ks][of] = *(const bf16x8*)&H;
      wf_lo[ks][of] = *(const bf16x8*)&L;
    }
  }
  __syncthreads();
  const f32x4 zero4 = {0.f,0.f,0.f,0.f};
  for (int chunk = 0; chunk < 2; ++chunk) {
    {
      int n = t >> 1;
      int kb = (t & 1) << 5;
      int nL = (chunk << 7) | n;
      float xa = xs[0][nL], xb = xs[1][nL], xc = xs[2][nL];
      char* rowh = (char*)&h1h[0][0] + (n << 7);
      char* rowl = (char*)&h1l[0][0] + (n << 7);
      int sw = (n & 7) << 4;
      #pragma unroll
      for (int kk = 0; kk < 32; kk += 2) {
        float4 wv0 = w1s4[kb + kk];
        float4 wv1 = w1s4[kb + kk + 1];
        float v0 = fmaxf(fmaf(wv0.x, xa, fmaf(wv0.y, xb, fmaf(wv0.z, xc, wv0.w))), 0.f);
        float v1 = fmaxf(fmaf(wv1.x, xa, fmaf(wv1.y, xb, fmaf(wv1.z, xc, wv1.w))), 0.f);
        u16 h0 = f2bf(v0), h1_ = f2bf(v1);
        u32 hw = (u32)h0 | ((u32)h1_ << 16);
        u32 lw = (u32)f2bf(v0 - bf2f(h0)) | ((u32)f2bf(v1 - bf2f(h1_)) << 16);
        int byte = ((kb + kk) << 1) ^ sw;
        *(u32*)(rowh + byte) = hw;
        *(u32*)(rowl + byte) = lw;
      }
    }
    __syncthreads();
    #pragma unroll
    for (int p = 0; p < 4; ++p) {
      int nrel = (wn << 6) | (p << 4) | (lane & 15);
      int abyte = (nrel << 7) | ((lane >> 4) << 4);
      int asw = (nrel & 7) << 4;
      f32x4 acc[4] = {zero4, zero4, zero4, zero4};
      #pragma unroll
      for (int ks = 0; ks < 2; ++ks) {
        int ad = (abyte | (ks << 6)) ^ asw;
        bf16x8 ah = *(const bf16x8*)((const char*)&h1h[0][0] + ad);
        bf16x8 al = *(const bf16x8*)((const char*)&h1l[0][0] + ad);
        #pragma unroll
        for (int of = 0; of < 4; ++of) {
          acc[of] = __builtin_amdgcn_mfma_f32_16x16x32_bf16(al, wf_hi[ks][of], acc[of], 0, 0, 0);
          acc[of] = __builtin_amdgcn_mfma_f32_16x16x32_bf16(ah, wf_lo[ks][of], acc[of], 0, 0, 0);
          acc[of] = __builtin_amdgcn_mfma_f32_16x16x32_bf16(ah, wf_hi[ks][of], acc[of], 0, 0, 0);
        }
      }
      int nbase = ntile | (chunk << 7) | (wn << 6) | (p << 4) | ((lane >> 4) << 2);
      #pragma unroll
      for (int of = 0; of < 4; ++of) {
        int o = (wo << 6) | (of << 4) | (lane & 15);
        #pragma unroll
        for (int r = 0; r < 4; ++r) {
          float v = fmaxf(acc[of][r] + bv[of], 0.f);
          u16 h = f2bf(v);
          u16 l = f2bf(v - bf2f(h));
          size_t gi = (((size_t)(b << 12) | (nbase + r)) << 7) | o;
          h2t_hi[gi] = h;
          h2t_lo[gi] = l;
        }
      }
    }
    __syncthreads();
  }
}

// ---------------- k5: bf16x3 MFMA 128->1024, counted-vmcnt pipeline ---------------
// 512 blocks = 8 xcd x 4 b x 8 otile(128 o) x 2 half(2048 n); 512 thr (8 waves).
// Wave owns o = otile*128 + wid*16. Chunk = 32 points (16KB hi+lo), 4 LDS buffers.
__global__ __launch_bounds__(512, 2) void k5_layer3(
    const u16* __restrict__ h2t_hi, const u16* __restrict__ h2t_lo,
    const float* __restrict__ w3,
    float* __restrict__ sum3, float* __restrict__ sq3,
    float* __restrict__ maxv, float* __restrict__ minv) {
  __shared__ __align__(16) char smem[65536];
  const int t = threadIdx.x;
  const int lane = t & 63;
  const int wid = t >> 6;
  const int id = blockIdx.x;
  const int xcd = id & 7, idx = id >> 3;
  const int b = (xcd << 2) | (idx >> 4);
  const int sub = idx & 15;
  const int otile = sub >> 1, half = sub & 1;

  // staging offsets (chunk-invariant): 16KB chunk = hi 8KB + lo 8KB
  const size_t gbase = ((size_t)b << 19) | ((size_t)half << 18);
  const int ldsu = (wid << 10) | (lane << 4);
  const int gboff = (ldsu ^ (((ldsu >> 8) & 7) << 4)) >> 1;   // u16 elements
  auto STAGE = [&](int c, int buf) {
    const u16* gh = h2t_hi + gbase + ((size_t)c << 12);
    const u16* gl = h2t_lo + gbase + ((size_t)c << 12);
    char* lb = smem + (buf << 14);
    __builtin_amdgcn_global_load_lds(
        (const __attribute__((address_space(1))) u32*)(gh + gboff),
        (__attribute__((address_space(3))) u32*)(lb + ldsu), 16, 0, 0);
    __builtin_amdgcn_global_load_lds(
        (const __attribute__((address_space(1))) u32*)(gl + gboff),
        (__attribute__((address_space(3))) u32*)(lb + 8192 + ldsu), 16, 0, 0);
  };
  STAGE(0, 0); STAGE(1, 1); STAGE(2, 2);   // 6 loads in flight

  // W3 frags -> registers (hi/lo): o = otile*128 + wid*16 + lane&15
  bf16x8 wf_hi[4], wf_lo[4];
  {
    int o = (otile << 7) | (wid << 4) | (lane & 15);
    #pragma unroll
    for (int ks = 0; ks < 4; ++ks) {
      const float* src = w3 + (size_t)o*128 + (ks << 5) + ((lane >> 4) << 3);
      float4 f0 = *(const float4*)src;
      float4 f1 = *(const float4*)(src + 4);
      float fv[8] = {f0.x,f0.y,f0.z,f0.w, f1.x,f1.y,f1.z,f1.w};
      u32 hw[4], lw[4];
      #pragma unroll
      for (int p2 = 0; p2 < 4; ++p2) {
        u16 h0 = f2bf(fv[2*p2]), h1 = f2bf(fv[2*p2+1]);
        u16 l0 = f2bf(fv[2*p2] - bf2f(h0)), l1 = f2bf(fv[2*p2+1] - bf2f(h1));
        hw[p2] = (u32)h0 | ((u32)h1 << 16);
        lw[p2] = (u32)l0 | ((u32)l1 << 16);
      }
      uint4 H = make_uint4(hw[0],hw[1],hw[2],hw[3]);
      uint4 L = make_uint4(lw[0],lw[1],lw[2],lw[3]);
      wf_hi[ks] = *(const bf16x8*)&H;
      wf_lo[ks] = *(const bf16x8*)&L;
    }
  }

  // A-frag addresses within a 8KB plane: rows nf*16 + lane&15, 256B row stride
  const int kb2 = (lane >> 4) << 4;
  const int n0base = (lane & 15) << 8;
  const int n1base = (16 | (lane & 15)) << 8;
  const int asw = ((lane & 15) & 7) << 4;

  f32x4 pv0, pv1;
  float rs0 = 0.f, rq0 = 0.f, rmx0 = -3.4e38f, rmn0 = 3.4e38f;
  float rs1 = 0.f, rq1 = 0.f, rmx1 = -3.4e38f, rmn1 = 3.4e38f;
  const f32x4 zero4 = {0.f,0.f,0.f,0.f};

  for (int h = 0; h < 64; ++h) {
    if (h < 62)      asm volatile("s_waitcnt vmcnt(4)" ::: "memory");
    else if (h == 62) asm volatile("s_waitcnt vmcnt(2)" ::: "memory");
    else              asm volatile("s_waitcnt vmcnt(0)" ::: "memory");
    asm volatile("s_barrier" ::: "memory");
    if (h < 61) STAGE(h + 3, (h + 3) & 3);
    const char* bufb = smem + ((h & 3) << 14);
    f32x4 A0, B0, C0, A1, B1, C1;
    __builtin_amdgcn_s_setprio(1);
    #pragma unroll
    for (int ks = 0; ks < 4; ++ks) {
      int off = (ks << 6) | kb2;
      int ad0 = (n0base | off) ^ asw;
      int ad1 = (n1base | off) ^ asw;
      bf16x8 ah0 = *(const bf16x8*)(bufb + ad0);
      bf16x8 al0 = *(const bf16x8*)(bufb + 8192 + ad0);
      bf16x8 ah1 = *(const bf16x8*)(bufb + ad1);
      bf16x8 al1 = *(const bf16x8*)(bufb + 8192 + ad1);
      A0 = __builtin_amdgcn_mfma_f32_16x16x32_bf16(al0, wf_hi[ks], ks ? A0 : zero4, 0, 0, 0);
      B0 = __builtin_amdgcn_mfma_f32_16x16x32_bf16(ah0, wf_lo[ks], ks ? B0 : zero4, 0, 0, 0);
      C0 = __builtin_amdgcn_mfma_f32_16x16x32_bf16(ah0, wf_hi[ks], ks ? C0 : zero4, 0, 0, 0);
      A1 = __builtin_amdgcn_mfma_f32_16x16x32_bf16(al1, wf_hi[ks], ks ? A1 : zero4, 0, 0, 0);
      B1 = __builtin_amdgcn_mfma_f32_16x16x32_bf16(ah1, wf_lo[ks], ks ? B1 : zero4, 0, 0, 0);
      C1 = __builtin_amdgcn_mfma_f32_16x16x32_bf16(ah1, wf_hi[ks], ks ? C1 : zero4, 0, 0, 0);
    }
    __builtin_amdgcn_s_setprio(0);
    // stats of PREVIOUS chunk's values (overlaps with the in-flight MFMAs)
    if (h > 0) {
      rs0 += (pv0[0] + pv0[1]) + (pv0[2] + pv0[3]);
      rq0 = fmaf(pv0[0],pv0[0], fmaf(pv0[1],pv0[1], fmaf(pv0[2],pv0[2], fmaf(pv0[3],pv0[3], rq0))));
      rmx0 = fmaxf(rmx0, fmaxf(fmaxf(pv0[0],pv0[1]), fmaxf(pv0[2],pv0[3])));
      rmn0 = fminf(rmn0, fminf(fminf(pv0[0],pv0[1]), fminf(pv0[2],pv0[3])));
      rs1 += (pv1[0] + pv1[1]) + (pv1[2] + pv1[3]);
      rq1 = fmaf(pv1[0],pv1[0], fmaf(pv1[1],pv1[1], fmaf(pv1[2],pv1[2], fmaf(pv1[3],pv1[3], rq1))));
      rmx1 = fmaxf(rmx1, fmaxf(fmaxf(pv1[0],pv1[1]), fmaxf(pv1[2],pv1[3])));
      rmn1 = fminf(rmn1, fminf(fminf(pv1[0],pv1[1]), fminf(pv1[2],pv1[3])));
    }
    pv0 = (A0 + B0) + C0;
    pv1 = (A1 + B1) + C1;
  }
  // final chunk's stats
  rs0 += (pv0[0] + pv0[1]) + (pv0[2] + pv0[3]);
  rq0 = fmaf(pv0[0],pv0[0], fmaf(pv0[1],pv0[1], fmaf(pv0[2],pv0[2], fmaf(pv0[3],pv0[3], rq0))));
  rmx0 = fmaxf(rmx0, fmaxf(fmaxf(pv0[0],pv0[1]), fmaxf(pv0[2],pv0[3])));
  rmn0 = fminf(rmn0, fminf(fminf(pv0[0],pv0[1]), fminf(pv0[2],pv0[3])));
  rs1 += (pv1[0] + pv1[1]) + (pv1[2] + pv1[3]);
  rq1 = fmaf(pv1[0],pv1[0], fmaf(pv1[1],pv1[1], fmaf(pv1[2],pv1[2], fmaf(pv1[3],pv1[3], rq1))));
  rmx1 = fmaxf(rmx1, fmaxf(fmaxf(pv1[0],pv1[1]), fmaxf(pv1[2],pv1[3])));
  rmn1 = fminf(rmn1, fminf(fminf(pv1[0],pv1[1]), fminf(pv1[2],pv1[3])));
  // merge nf halves (same o), then cross-lane over the 4 k-groups (o preserved)
  float RS = rs0 + rs1, RQ = rq0 + rq1;
  float MX = fmaxf(rmx0, rmx1), MN = fminf(rmn0, rmn1);
  RS += __shfl_xor(RS, 16); RS += __shfl_xor(RS, 32);
  RQ += __shfl_xor(RQ, 16); RQ += __shfl_xor(RQ, 32);
  MX = fmaxf(MX, __shfl_xor(MX, 16)); MX = fmaxf(MX, __shfl_xor(MX, 32));
  MN = fminf(MN, __shfl_xor(MN, 16)); MN = fminf(MN, __shfl_xor(MN, 32));
  if (lane < 16) {
    int go = (((half << 5) | b) << 10) | (otile << 7) | (wid << 4) | lane;
    sum3[go] = RS; sq3[go] = RQ; maxv[go] = MX; minv[go] = MN;
  }
}

// ---------------- finalize stats3 (+bias fold) + pooled ---------------------------
__global__ void k_fin3_pool(const float* __restrict__ sum3, const float* __restrict__ sq3,
    const float* __restrict__ maxv, const float* __restrict__ minv,
    const float* __restrict__ b3,
    const float* __restrict__ g, const float* __restrict__ be, float* __restrict__ pool) {
  int o = blockIdx.x*256 + threadIdx.x;
  float S = 0.f, Q = 0.f;
  for (int h = 0; h < 2; ++h)
    for (int b = 0; b < 32; ++b) { int gi = (((h<<5)|b)<<10) | o; S += sum3[gi]; Q += sq3[gi]; }
  const float inv = 1.f/131072.f;
  float ma = S*inv;
  float m = ma + b3[o];
  float var = Q*inv - ma*ma;
  float sc = g[o]*rsqrtf(var + EPS);
  float sh = be[o] - sc*m;
  bool pos = (sc >= 0.f);
  for (int b = 0; b < 32; ++b) {
    int g0 = (b << 10) | o, g1 = ((32 + b) << 10) | o;
    float v = pos ? fmaxf(maxv[g0], maxv[g1]) : fminf(minv[g0], minv[g1]);
    pool[(b << 10) | o] = fmaxf(fmaf(sc, v + b3[o], sh), 0.f);
  }
}

// ---------------- fused FC + batch-BN + ReLU --------------------------------------
__global__ __launch_bounds__(256) void k_fc_bn_relu(const float* __restrict__ in,
    const float* __restrict__ w, const float* __restrict__ fb,
    const float* __restrict__ g, const float* __restrict__ be,
    float* __restrict__ out, int K, int F) {
  __shared__ float wrow[1024];
  __shared__ float preb[32];
  int o = blockIdx.x, t = threadIdx.x;
  for (int k = t; k < K; k += 256) wrow[k] = w[(size_t)o*K + k];
  __syncthreads();
  int b = t >> 3, j = t & 7;
  int per = K >> 3;
  const float* inb = in + (size_t)b*K + j*per;
  const float* wp  = wrow + j*per;
  float p = 0.f;
  for (int k = 0; k < per; ++k) p = fmaf(inb[k], wp[k], p);
  p += __shfl_xor(p, 1); p += __shfl_xor(p, 2); p += __shfl_xor(p, 4);
  if (j == 0) preb[b] = p + fb[o];
  __syncthreads();
  if (t < 32) {
    float v = preb[t];
    float s = v;
    #pragma unroll
    for (int d = 1; d < 32; d <<= 1) s += __shfl_xor(s, d);
    float m = s * 0.03125f;
    float dv = v - m;
    float q = dv*dv;
    #pragma unroll
    for (int d = 1; d < 32; d <<= 1) q += __shfl_xor(q, d);
    float var = q * 0.03125f;
    float sc = g[o]*rsqrtf(var + EPS);
    out[(size_t)t*F + o] = fmaxf(fmaf(sc, dv, be[o]), 0.f);
  }
}

// ---------------- angles + Euler->rotation ----------------------------------------
__global__ __launch_bounds__(128) void k_final(const float* __restrict__ h6,
    const float* __restrict__ fw4, const float* __restrict__ fb4, float* __restrict__ out) {
  __shared__ float angs[32][3];
  int t = threadIdx.x;
  if (t < 96) {
    int b = t / 3, j = t % 3;
    float p = 0.f;
    #pragma unroll 4
    for (int k = 0; k < 128; ++k) p = fmaf(h6[b*128+k], fw4[j*128+k], p);
    angs[b][j] = (p + fb4[j]) * PI_F;
  }
  __syncthreads();
  if (t < 32) {
    float a = angs[t][0], bb = angs[t][1], c = angs[t][2];
    float sa, ca; sincosf(a,  &sa, &ca);
    float sb, cb; sincosf(bb, &sb, &cb);
    float sc, cc; sincosf(c,  &sc, &cc);
    float* o9 = out + t*9;
    o9[0] = cc*cb;
    o9[1] = fmaf(cc*sb, sa, -sc*ca);
    o9[2] = fmaf(cc*sb, ca,  sc*sa);
    o9[3] = sc*cb;
    o9[4] = fmaf(sc*sb, sa,  cc*ca);
    o9[5] = fmaf(sc*sb, ca, -cc*sa);
    o9[6] = -sb;
    o9[7] = cb*sa;
    o9[8] = cb*ca;
  }
}

extern "C" void kernel_launch(void* const* d_in, const int* in_sizes, int n_in,
                              void* d_out, int out_size, void* d_ws, size_t ws_size,
                              hipStream_t stream) {
  (void)in_sizes; (void)n_in; (void)out_size; (void)ws_size;
  const float* x   = (const float*)d_in[0];
  const float* w1  = (const float*)d_in[1];
  const float* b1  = (const float*)d_in[2];
  const float* g1  = (const float*)d_in[3];
  const float* be1 = (const float*)d_in[4];
  const float* w2  = (const float*)d_in[5];
  const float* b2  = (const float*)d_in[6];
  const float* g2  = (const float*)d_in[7];
  const float* be2 = (const float*)d_in[8];
  const float* w3  = (const float*)d_in[9];
  const float* b3  = (const float*)d_in[10];
  const float* g3  = (const float*)d_in[11];
  const float* be3 = (const float*)d_in[12];
  const float* fw1 = (const float*)d_in[13];
  const float* fb1 = (const float*)d_in[14];
  const float* g4  = (const float*)d_in[15];
  const float* be4 = (const float*)d_in[16];
  const float* fw2 = (const float*)d_in[17];
  const float* fb2 = (const float*)d_in[18];
  const float* g5p = (const float*)d_in[19];
  const float* be5 = (const float*)d_in[20];
  const float* fw3 = (const float*)d_in[21];
  const float* fb3 = (const float*)d_in[22];
  const float* g6  = (const float*)d_in[23];
  const float* be6 = (const float*)d_in[24];
  const float* fw4 = (const float*)d_in[25];
  const float* fb4 = (const float*)d_in[26];

  u16* h2t_hi = (u16*)d_ws;                     // 32 MiB
  u16* h2t_lo = (u16*)d_ws + 16777216;          // 32 MiB
  float* gram_part = (float*)d_ws;              // 8 MiB, aliases h2t (pre-kE2 only)
  float* acc0 = (float*)d_ws + 16777216;
  float* xst  = acc0;                           // 16
  float* m1v  = acc0 + 16;                      // 64
  float* gram = acc0 + 80;                      // 4096
  float* w1f  = acc0 + 4176;                    // 192
  float* b1f  = acc0 + 4368;                    // 64
  float* w2f  = acc0 + 4432;                    // 8192
  float* b2f  = acc0 + 12624;                   // 128
  float* sum3 = acc0 + 12752;                   // 2*32*1024
  float* sq3  = acc0 + 78288;
  float* maxv = acc0 + 143824;
  float* minv = acc0 + 209360;
  float* pool = acc0 + 274896;                  // 32768
  float* h4v  = acc0 + 307664;                  // 16384
  float* h5v  = acc0 + 324048;                  // 8192
  float* h6v  = acc0 + 332240;                  // 4096

  hipMemsetAsync(acc0, 0, 80ull*4, stream);     // xst + m1v

  kA_xstats<<<128, 256, 0, stream>>>(x, xst);
  kB_fold1<<<1, 64, 0, stream>>>(xst, w1, b1, g1, be1, w1f, b1f);
  kC_gram<<<512, 256, 0, stream>>>(x, w1f, b1f, gram_part, m1v);
  kR_gramred<<<16, 256, 0, stream>>>(gram_part, gram);
  kD_fold2<<<128, 64, 0, stream>>>(gram, m1v, w2, b2, g2, be2, w2f, b2f);
  kE2_layer2<<<512, 256, 0, stream>>>(x, w1f, b1f, w2f, b2f, h2t_hi, h2t_lo);
  k5_layer3<<<512, 512, 0, stream>>>(h2t_hi, h2t_lo, w3, sum3, sq3, maxv, minv);
  k_fin3_pool<<<4, 256, 0, stream>>>(sum3, sq3, maxv, minv, b3, g3, be3, pool);
  k_fc_bn_relu<<<512, 256, 0, stream>>>(pool, fw1, fb1, g4, be4, h4v, 1024, 512);
  k_fc_bn_relu<<<256, 256, 0, stream>>>(h4v, fw2, fb2, g5p, be5, h5v, 512, 256);
  k_fc_bn_relu<<<128, 256, 0, stream>>>(h5v, fw3, fb3, g6, be6, h6v, 256, 128);
  k_final<<<1, 128, 0, stream>>>(h6v, fw4, fb4, (float*)d_out);
}

// Round 7
// 266.411 us; speedup vs baseline: 1.5691x; 1.0234x over previous
//
#include <hip/hip_runtime.h>
#include <math.h>

// STN3d, B=32, C=3, N=4096. Training-mode BN (batch stats), moment-folded.
// h2t is stored in MFMA-FRAGMENT-MAJOR order (per plane):
//   element (b, n, k): nblk=n>>4, ks=k>>5, l=(n&15)|(((k>>3)&3)<<4), j=k&7
//   u16 idx = (((b*256+nblk)*4+ks)*512) + l*8 + j      (frag = 1KB, lane-major)
// -> k5 staging/ds_reads are fully linear (zero bank conflicts),
// -> kE2 stores are packed ushort4, 512B contiguous per wave instruction.

#define EPS 1e-5f
#define PI_F 3.1415927410125732f

typedef unsigned int u32;
typedef unsigned short u16;
typedef __bf16 bf16x8 __attribute__((ext_vector_type(8)));
typedef float f32x4 __attribute__((ext_vector_type(4)));

__device__ __forceinline__ u16 f2bf(float f) {
  u32 u = __float_as_uint(f);
  return (u16)((u + 0x7FFFu + ((u >> 16) & 1u)) >> 16);
}
__device__ __forceinline__ float bf2f(u16 h) { return __uint_as_float(((u32)h) << 16); }

// ---------------- kA: x second moments (9 sums) -----------------------------------
__global__ __launch_bounds__(256) void kA_xstats(const float* __restrict__ x,
    float* __restrict__ xst) {
  int tg = blockIdx.x * 256 + threadIdx.x;
  int b = tg >> 10, nq = (tg & 1023) << 2;
  const float* xb = x + ((size_t)b * 3) * 4096 + nq;
  float4 a = *(const float4*)(xb);
  float4 c = *(const float4*)(xb + 4096);
  float4 d = *(const float4*)(xb + 8192);
  float p[9];
  p[0] = (a.x + a.y) + (a.z + a.w);
  p[1] = (c.x + c.y) + (c.z + c.w);
  p[2] = (d.x + d.y) + (d.z + d.w);
  p[3] = fmaf(a.x,a.x, fmaf(a.y,a.y, fmaf(a.z,a.z, a.w*a.w)));
  p[4] = fmaf(a.x,c.x, fmaf(a.y,c.y, fmaf(a.z,c.z, a.w*c.w)));
  p[5] = fmaf(a.x,d.x, fmaf(a.y,d.y, fmaf(a.z,d.z, a.w*d.w)));
  p[6] = fmaf(c.x,c.x, fmaf(c.y,c.y, fmaf(c.z,c.z, c.w*c.w)));
  p[7] = fmaf(c.x,d.x, fmaf(c.y,d.y, fmaf(c.z,d.z, c.w*d.w)));
  p[8] = fmaf(d.x,d.x, fmaf(d.y,d.y, fmaf(d.z,d.z, d.w*d.w)));
  #pragma unroll
  for (int k = 0; k < 9; ++k) {
    #pragma unroll
    for (int s = 1; s < 64; s <<= 1) p[k] += __shfl_xor(p[k], s);
  }
  if ((threadIdx.x & 63) == 0) {
    #pragma unroll
    for (int k = 0; k < 9; ++k) atomicAdd(&xst[k], p[k]);
  }
}

// ---------------- kB: fold BN1 into W1 --------------------------------------------
__global__ void kB_fold1(const float* __restrict__ xst,
    const float* __restrict__ w1, const float* __restrict__ b1,
    const float* __restrict__ g1, const float* __restrict__ be1,
    float* __restrict__ w1f, float* __restrict__ b1f) {
  int o = threadIdx.x;
  const float inv = 1.f / 131072.f;
  float mx = xst[0]*inv, my = xst[1]*inv, mz = xst[2]*inv;
  float cxx = xst[3]*inv - mx*mx, cxy = xst[4]*inv - mx*my, cxz = xst[5]*inv - mx*mz;
  float cyy = xst[6]*inv - my*my, cyz = xst[7]*inv - my*mz, czz = xst[8]*inv - mz*mz;
  float wa = w1[o*3], wb = w1[o*3+1], wc = w1[o*3+2];
  float mu = fmaf(wa, mx, fmaf(wb, my, fmaf(wc, mz, b1[o])));
  float var = wa*wa*cxx + wb*wb*cyy + wc*wc*czz
            + 2.f*(wa*wb*cxy + wa*wc*cxz + wb*wc*cyz);
  float s = g1[o] * rsqrtf(var + EPS);
  w1f[o*3]   = s*wa;
  w1f[o*3+1] = s*wb;
  w1f[o*3+2] = s*wc;
  b1f[o] = be1[o] + s*(b1[o] - mu);
}

// ---------------- kC: Gram of h1 (64x64) + column sums ----------------------------
__global__ __launch_bounds__(256) void kC_gram(const float* __restrict__ x,
    const float* __restrict__ w1f, const float* __restrict__ b1f,
    float* __restrict__ gram_part, float* __restrict__ m1v) {
  __shared__ float xs[3][64];
  __shared__ float tile[64][64];
  __shared__ float mred[256];
  int t = threadIdx.x;
  int ch = t & 63;
  float wa = w1f[ch*3], wb = w1f[ch*3+1], wc = w1f[ch*3+2], bf = b1f[ch];
  int ti = t & 7, tj = (t >> 3) & 7, ph = t >> 6;
  int i0 = ti << 3, j0 = tj << 3, p0 = ph << 4;
  float gacc[8][8];
  #pragma unroll
  for (int a = 0; a < 8; ++a)
    #pragma unroll
    for (int c = 0; c < 8; ++c) gacc[a][c] = 0.f;
  float msum = 0.f;
  for (int it = 0; it < 4; ++it) {
    int tile_id = blockIdx.x * 4 + it;
    int bb = tile_id >> 6, n0 = (tile_id & 63) << 6;
    if (t < 192) { int c = t >> 6, n = t & 63; xs[c][n] = x[((size_t)bb*3 + c)*4096 + n0 + n]; }
    __syncthreads();
    #pragma unroll
    for (int r = 0; r < 16; ++r) {
      int pt = (r << 2) | (t >> 6);
      float v = fmaxf(fmaf(wa, xs[0][pt], fmaf(wb, xs[1][pt], fmaf(wc, xs[2][pt], bf))), 0.f);
      tile[pt][ch] = v;
      msum += v;
    }
    __syncthreads();
    #pragma unroll 4
    for (int q = 0; q < 16; ++q) {
      int pt = p0 + q;
      float4 a0 = *(const float4*)(&tile[pt][i0]);
      float4 a1 = *(const float4*)(&tile[pt][i0 + 4]);
      float4 c0 = *(const float4*)(&tile[pt][j0]);
      float4 c1 = *(const float4*)(&tile[pt][j0 + 4]);
      float ai[8] = {a0.x,a0.y,a0.z,a0.w, a1.x,a1.y,a1.z,a1.w};
      float aj[8] = {c0.x,c0.y,c0.z,c0.w, c1.x,c1.y,c1.z,c1.w};
      #pragma unroll
      for (int a = 0; a < 8; ++a)
        #pragma unroll
        for (int c = 0; c < 8; ++c) gacc[a][c] = fmaf(ai[a], aj[c], gacc[a][c]);
    }
    __syncthreads();
  }
  mred[t] = msum;
  __syncthreads();
  if (t < 64) atomicAdd(&m1v[t], mred[t] + mred[t+64] + mred[t+128] + mred[t+192]);
  float* gl = &tile[0][0];
  if (ph == 0) {
    #pragma unroll
    for (int a = 0; a < 8; ++a)
      #pragma unroll
      for (int c = 0; c < 8; ++c) gl[(i0+a)*64 + j0 + c] = gacc[a][c];
  }
  __syncthreads();
  #pragma unroll
  for (int p = 1; p < 4; ++p) {
    if (ph == p) {
      #pragma unroll
      for (int a = 0; a < 8; ++a)
        #pragma unroll
        for (int c = 0; c < 8; ++c) gl[(i0+a)*64 + j0 + c] += gacc[a][c];
    }
    __syncthreads();
  }
  float* gp = gram_part + (size_t)blockIdx.x * 4096;
  #pragma unroll
  for (int r = 0; r < 16; ++r) gp[r*256 + t] = gl[r*256 + t];
}

// ---------------- kR: reduce gram partials ----------------------------------------
__global__ __launch_bounds__(256) void kR_gramred(const float* __restrict__ gram_part,
    float* __restrict__ gram) {
  int cell = blockIdx.x * 256 + threadIdx.x;
  float s = 0.f;
  for (int blk = 0; blk < 512; ++blk) s += gram_part[(size_t)blk*4096 + cell];
  gram[cell] = s;
}

// ---------------- kD: fold BN2 into W2 --------------------------------------------
__global__ void kD_fold2(const float* __restrict__ gram, const float* __restrict__ m1v,
    const float* __restrict__ w2, const float* __restrict__ b2,
    const float* __restrict__ g2, const float* __restrict__ be2,
    float* __restrict__ w2f, float* __restrict__ b2f) {
  __shared__ float wrow[64];
  int o = blockIdx.x, i = threadIdx.x;
  wrow[i] = w2[o*64 + i];
  __syncthreads();
  const float inv = 1.f / 131072.f;
  float si = 0.f;
  #pragma unroll 8
  for (int j = 0; j < 64; ++j) si = fmaf(wrow[j], gram[j*64 + i], si);
  float qi = wrow[i] * si;
  float di = wrow[i] * (m1v[i] * inv);
  #pragma unroll
  for (int d2 = 1; d2 < 64; d2 <<= 1) { qi += __shfl_xor(qi, d2); di += __shfl_xor(di, d2); }
  float mu2 = di + b2[o];
  float var = qi*inv - di*di;
  float s = g2[o] * rsqrtf(var + EPS);
  w2f[o*64 + i] = s * wrow[i];
  if (i == 0) b2f[o] = be2[o] + s*(b2[o] - mu2);
}

// ---------------- kE2: layer2 bf16x3 MFMA -> relu -> hi/lo -> frag-major h2t ------
// 512 blocks (b x 16 n-tiles of 256), 256 thr = 4 waves (wo: 64-k half, wn: 128-n half).
// MFMA operands swapped (A=w2 frags, B=h1 frags) so D rows = k-dim -> each thread
// holds 4 consecutive k at one n -> packed ushort4 stores, fully coalesced.
__global__ __launch_bounds__(256) void kE2_layer2(const float* __restrict__ x,
    const float* __restrict__ w1f, const float* __restrict__ b1f,
    const float* __restrict__ w2f, const float* __restrict__ b2f,
    u16* __restrict__ h2t_hi, u16* __restrict__ h2t_lo) {
  __shared__ float xs[3][256];
  __shared__ float4 w1s4[64];
  __shared__ __align__(16) char h1h[17408];   // 16 frags x (1024B + 64B pad)
  __shared__ __align__(16) char h1l[17408];
  int t = threadIdx.x;
  int b = ((blockIdx.x & 7) << 2) | ((blockIdx.x >> 3) & 3);
  int ntile = (blockIdx.x >> 5) << 8;
  int lane = t & 63, wid = t >> 6;
  int wo = wid & 1, wn = wid >> 1;
  #pragma unroll
  for (int i = 0; i < 3; ++i) {
    int idx = (i << 8) | t;
    int c = idx >> 8, n = idx & 255;
    xs[c][n] = x[((size_t)b*3 + c)*4096 + ntile + n];
  }
  if (t < 64) w1s4[t] = make_float4(w1f[t*3], w1f[t*3+1], w1f[t*3+2], b1f[t]);
  // A-frags: w2f rows o2 = wo*64 + of*16 + (lane&15), k1-slice (lane>>4)*8
  bf16x8 wf_hi[4][2], wf_lo[4][2];    // [of][ks1]
  float4 bvv[4];
  #pragma unroll
  for (int of = 0; of < 4; ++of) {
    int o2r = (wo << 6) | (of << 4) | (lane & 15);
    bvv[of] = *(const float4*)(b2f + (wo << 6) + (of << 4) + ((lane >> 4) << 2));
    #pragma unroll
    for (int ks1 = 0; ks1 < 2; ++ks1) {
      const float* src = w2f + o2r*64 + (ks1 << 5) + ((lane >> 4) << 3);
      float4 f0 = *(const float4*)src;
      float4 f1 = *(const float4*)(src + 4);
      float fv[8] = {f0.x,f0.y,f0.z,f0.w, f1.x,f1.y,f1.z,f1.w};
      u32 hw[4], lw[4];
      #pragma unroll
      for (int p2 = 0; p2 < 4; ++p2) {
        u16 h0 = f2bf(fv[2*p2]), h1 = f2bf(fv[2*p2+1]);
        u16 l0 = f2bf(fv[2*p2] - bf2f(h0)), l1 = f2bf(fv[2*p2+1] - bf2f(h1));
        hw[p2] = (u32)h0 | ((u32)h1 << 16);
        lw[p2] = (u32)l0 | ((u32)l1 << 16);
      }
      uint4 H = make_uint4(hw[0],hw[1],hw[2],hw[3]);
      uint4 L = make_uint4(lw[0],lw[1],lw[2],lw[3]);
      wf_hi[of][ks1] = *(const bf16x8*)&H;
      wf_lo[of][ks1] = *(const bf16x8*)&L;
    }
  }
  __syncthreads();
  const f32x4 zero4 = {0.f,0.f,0.f,0.f};
  for (int chunk = 0; chunk < 2; ++chunk) {
    {   // h1 build: thread = (n = t>>1, k1-half ks1 = t&1), frag-major write
      int n = t >> 1, ks1 = t & 1;
      int nL = (chunk << 7) | n;
      float xa = xs[0][nL], xb = xs[1][nL], xc = xs[2][nL];
      int fb = (((n >> 4) << 1) | ks1) * 1088 + ((n & 15) << 4);
      #pragma unroll
      for (int kq = 0; kq < 4; ++kq) {
        u32 hw[4], lw[4];
        #pragma unroll
        for (int p2 = 0; p2 < 4; ++p2) {
          int k1 = (ks1 << 5) | (kq << 3) | (p2 << 1);
          float4 wv0 = w1s4[k1];
          float4 wv1 = w1s4[k1 + 1];
          float v0 = fmaxf(fmaf(wv0.x, xa, fmaf(wv0.y, xb, fmaf(wv0.z, xc, wv0.w))), 0.f);
          float v1 = fmaxf(fmaf(wv1.x, xa, fmaf(wv1.y, xb, fmaf(wv1.z, xc, wv1.w))), 0.f);
          u16 h0 = f2bf(v0), h1_ = f2bf(v1);
          hw[p2] = (u32)h0 | ((u32)h1_ << 16);
          lw[p2] = (u32)f2bf(v0 - bf2f(h0)) | ((u32)f2bf(v1 - bf2f(h1_)) << 16);
        }
        *(uint4*)(h1h + fb + (kq << 8)) = make_uint4(hw[0],hw[1],hw[2],hw[3]);
        *(uint4*)(h1l + fb + (kq << 8)) = make_uint4(lw[0],lw[1],lw[2],lw[3]);
      }
    }
    __syncthreads();
    #pragma unroll
    for (int nb = 0; nb < 4; ++nb) {
      int fbase = (((wn << 2) | nb) << 1) * 1088 + (lane << 4);
      bf16x8 bh0 = *(const bf16x8*)(h1h + fbase);
      bf16x8 bh1 = *(const bf16x8*)(h1h + fbase + 1088);
      bf16x8 bl0 = *(const bf16x8*)(h1l + fbase);
      bf16x8 bl1 = *(const bf16x8*)(h1l + fbase + 1088);
      int nblk_g = (ntile >> 4) | (chunk << 3) | (wn << 2) | nb;
      #pragma unroll
      for (int of = 0; of < 4; ++of) {
        f32x4 acc;
        acc = __builtin_amdgcn_mfma_f32_16x16x32_bf16(wf_hi[of][0], bl0, zero4, 0, 0, 0);
        acc = __builtin_amdgcn_mfma_f32_16x16x32_bf16(wf_lo[of][0], bh0, acc, 0, 0, 0);
        acc = __builtin_amdgcn_mfma_f32_16x16x32_bf16(wf_hi[of][0], bh0, acc, 0, 0, 0);
        acc = __builtin_amdgcn_mfma_f32_16x16x32_bf16(wf_hi[of][1], bl1, acc, 0, 0, 0);
        acc = __builtin_amdgcn_mfma_f32_16x16x32_bf16(wf_lo[of][1], bh1, acc, 0, 0, 0);
        acc = __builtin_amdgcn_mfma_f32_16x16x32_bf16(wf_hi[of][1], bh1, acc, 0, 0, 0);
        // bias + relu + split + packed store (4 consecutive k at one n)
        ushort4 hs, ls;
        float v0 = fmaxf(acc[0] + bvv[of].x, 0.f);
        float v1 = fmaxf(acc[1] + bvv[of].y, 0.f);
        float v2 = fmaxf(acc[2] + bvv[of].z, 0.f);
        float v3 = fmaxf(acc[3] + bvv[of].w, 0.f);
        hs.x = f2bf(v0); hs.y = f2bf(v1); hs.z = f2bf(v2); hs.w = f2bf(v3);
        ls.x = f2bf(v0 - bf2f(hs.x)); ls.y = f2bf(v1 - bf2f(hs.y));
        ls.z = f2bf(v2 - bf2f(hs.z)); ls.w = f2bf(v3 - bf2f(hs.w));
        int ks2 = (wo << 1) | (of >> 1);
        int q = ((of & 1) << 1) | ((lane >> 5) & 1);
        int l = (lane & 15) | (q << 4);
        int j0 = ((lane >> 4) & 1) << 2;
        size_t idx = ((((size_t)((b << 8) | nblk_g) << 2) | ks2) << 9) + (l << 3) + j0;
        *(ushort4*)(h2t_hi + idx) = hs;
        *(ushort4*)(h2t_lo + idx) = ls;
      }
    }
    __syncthreads();
  }
}

// ---------------- k5: bf16x3 MFMA 128->1024, frag-major LDS, counted-vmcnt --------
// 512 blocks; id%8 groups blocks sharing (b,half) on one XCD.
// 512 thr = 8 waves (wo in [0,4): 32-o group, wn in [0,2): 16-n group of the chunk).
// Chunk = 32 points: hi 8KB + lo 8KB, fully linear staging and ds_reads.
__global__ __launch_bounds__(512, 2) void k5_layer3(
    const u16* __restrict__ h2t_hi, const u16* __restrict__ h2t_lo,
    const float* __restrict__ w3,
    float* __restrict__ sum3, float* __restrict__ sq3,
    float* __restrict__ maxv, float* __restrict__ minv) {
  __shared__ __align__(16) char smem[65536];     // 4 x 16KB chunk buffers
  const int t = threadIdx.x;
  const int lane = t & 63;
  const int wid = t >> 6;
  const int wo = wid & 3, wn = wid >> 2;
  const int id = blockIdx.x;
  const int b2h = (((id >> 3) & 7) << 3) | (id & 7);
  const int otile = id >> 6;
  const int b = b2h >> 1, half = b2h & 1;

  // staging: per chunk per plane, 512 thr x 16B = 8KB fully contiguous
  const size_t gchunk0 = ((size_t)((b << 8) | (half << 7))) << 11;  // u16
  const int ldsw = wid << 10;                    // wave-uniform LDS base
  auto STAGE = [&](int c, int buf) {
    size_t gb = gchunk0 + ((size_t)c << 12) + ((size_t)t << 3);
    char* lb = smem + (buf << 14);
    __builtin_amdgcn_global_load_lds(
        (const __attribute__((address_space(1))) u32*)(h2t_hi + gb),
        (__attribute__((address_space(3))) u32*)(lb + ldsw), 16, 0, 0);
    __builtin_amdgcn_global_load_lds(
        (const __attribute__((address_space(1))) u32*)(h2t_lo + gb),
        (__attribute__((address_space(3))) u32*)(lb + 8192 + ldsw), 16, 0, 0);
  };
  STAGE(0, 0); STAGE(1, 1); STAGE(2, 2);

  // W3 frags (hi/lo): o3 = otile*128 + wo*32 + of*16 + (lane&15)
  bf16x8 wf_hi[4][2], wf_lo[4][2];    // [ks][of]
  #pragma unroll
  for (int of = 0; of < 2; ++of) {
    int o3 = (otile << 7) | (wo << 5) | (of << 4) | (lane & 15);
    #pragma unroll
    for (int ks = 0; ks < 4; ++ks) {
      const float* src = w3 + (size_t)o3*128 + (ks << 5) + ((lane >> 4) << 3);
      float4 f0 = *(const float4*)src;
      float4 f1 = *(const float4*)(src + 4);
      float fv[8] = {f0.x,f0.y,f0.z,f0.w, f1.x,f1.y,f1.z,f1.w};
      u32 hw[4], lw[4];
      #pragma unroll
      for (int p2 = 0; p2 < 4; ++p2) {
        u16 h0 = f2bf(fv[2*p2]), h1 = f2bf(fv[2*p2+1]);
        u16 l0 = f2bf(fv[2*p2] - bf2f(h0)), l1 = f2bf(fv[2*p2+1] - bf2f(h1));
        hw[p2] = (u32)h0 | ((u32)h1 << 16);
        lw[p2] = (u32)l0 | ((u32)l1 << 16);
      }
      uint4 H = make_uint4(hw[0],hw[1],hw[2],hw[3]);
      uint4 L = make_uint4(lw[0],lw[1],lw[2],lw[3]);
      wf_hi[ks][of] = *(const bf16x8*)&H;
      wf_lo[ks][of] = *(const bf16x8*)&L;
    }
  }

  float rs[2] = {0.f,0.f}, rq[2] = {0.f,0.f};
  float rmx[2] = {-3.4e38f,-3.4e38f}, rmn[2] = {3.4e38f,3.4e38f};
  const f32x4 zero4 = {0.f,0.f,0.f,0.f};
  f32x4 cA0, cA1, cB0, cB1;

#define K5_CHUNK(H, X0, X1) do {                                               \
    int h_ = (H);                                                              \
    if (h_ < 62)       asm volatile("s_waitcnt vmcnt(4)" ::: "memory");        \
    else if (h_ == 62) asm volatile("s_waitcnt vmcnt(2)" ::: "memory");        \
    else               asm volatile("s_waitcnt vmcnt(0)" ::: "memory");        \
    __builtin_amdgcn_s_barrier();                                              \
    if (h_ < 61) STAGE(h_ + 3, (h_ + 3) & 3);                                  \
    const char* bb_ = smem + ((h_ & 3) << 14) + (wn << 12) + (lane << 4);      \
    __builtin_amdgcn_s_setprio(1);                                             \
    _Pragma("unroll")                                                          \
    for (int ks = 0; ks < 4; ++ks) {                                           \
      bf16x8 ah = *(const bf16x8*)(bb_ + (ks << 10));                          \
      bf16x8 al = *(const bf16x8*)(bb_ + 8192 + (ks << 10));                   \
      X0 = __builtin_amdgcn_mfma_f32_16x16x32_bf16(al, wf_hi[ks][0], ks ? X0 : zero4, 0, 0, 0); \
      X0 = __builtin_amdgcn_mfma_f32_16x16x32_bf16(ah, wf_lo[ks][0], X0, 0, 0, 0); \
      X0 = __builtin_amdgcn_mfma_f32_16x16x32_bf16(ah, wf_hi[ks][0], X0, 0, 0, 0); \
      X1 = __builtin_amdgcn_mfma_f32_16x16x32_bf16(al, wf_hi[ks][1], ks ? X1 : zero4, 0, 0, 0); \
      X1 = __builtin_amdgcn_mfma_f32_16x16x32_bf16(ah, wf_lo[ks][1], X1, 0, 0, 0); \
      X1 = __builtin_amdgcn_mfma_f32_16x16x32_bf16(ah, wf_hi[ks][1], X1, 0, 0, 0); \
    }                                                                          \
    __builtin_amdgcn_s_setprio(0);                                             \
  } while (0)

#define K5_STATS(X0, X1) do {                                                  \
    rs[0] += (X0[0] + X0[1]) + (X0[2] + X0[3]);                                \
    rq[0] = fmaf(X0[0],X0[0], fmaf(X0[1],X0[1], fmaf(X0[2],X0[2], fmaf(X0[3],X0[3], rq[0])))); \
    rmx[0] = fmaxf(rmx[0], fmaxf(fmaxf(X0[0],X0[1]), fmaxf(X0[2],X0[3])));     \
    rmn[0] = fminf(rmn[0], fminf(fminf(X0[0],X0[1]), fminf(X0[2],X0[3])));     \
    rs[1] += (X1[0] + X1[1]) + (X1[2] + X1[3]);                                \
    rq[1] = fmaf(X1[0],X1[0], fmaf(X1[1],X1[1], fmaf(X1[2],X1[2], fmaf(X1[3],X1[3], rq[1])))); \
    rmx[1] = fmaxf(rmx[1], fmaxf(fmaxf(X1[0],X1[1]), fmaxf(X1[2],X1[3])));     \
    rmn[1] = fminf(rmn[1], fminf(fminf(X1[0],X1[1]), fminf(X1[2],X1[3])));     \
  } while (0)

  K5_CHUNK(0, cA0, cA1);
  K5_CHUNK(1, cB0, cB1);
  K5_STATS(cA0, cA1);
  for (int hh = 1; hh < 32; ++hh) {
    K5_CHUNK(2*hh, cA0, cA1);
    K5_STATS(cB0, cB1);
    K5_CHUNK(2*hh + 1, cB0, cB1);
    K5_STATS(cA0, cA1);
  }
  K5_STATS(cB0, cB1);
#undef K5_CHUNK
#undef K5_STATS

  // cross-lane: o = lane&15 preserved under xor 16/32
  #pragma unroll
  for (int of = 0; of < 2; ++of) {
    rs[of] += __shfl_xor(rs[of], 16); rs[of] += __shfl_xor(rs[of], 32);
    rq[of] += __shfl_xor(rq[of], 16); rq[of] += __shfl_xor(rq[of], 32);
    rmx[of] = fmaxf(rmx[of], __shfl_xor(rmx[of], 16)); rmx[of] = fmaxf(rmx[of], __shfl_xor(rmx[of], 32));
    rmn[of] = fminf(rmn[of], __shfl_xor(rmn[of], 16)); rmn[of] = fminf(rmn[of], __shfl_xor(rmn[of], 32));
  }
  // cross-wn reduce via LDS (two waves share the same o range when wo equal)
  __builtin_amdgcn_s_barrier();
  float* part = (float*)smem;   // [wn][wo][2 of][16 o][4 stats] = 2*4*2*16*4 floats
  if (lane < 16) {
    #pragma unroll
    for (int of = 0; of < 2; ++of) {
      float* pp = part + ((((((wn << 2) | wo) << 1) | of) << 4) + lane) * 4;
      pp[0] = rs[of]; pp[1] = rq[of]; pp[2] = rmx[of]; pp[3] = rmn[of];
    }
  }
  __syncthreads();
  if (t < 128) {     // t = wo(2b)|of(1b)|o(4b) -> 128 outputs
    int wo_ = t >> 5, of_ = (t >> 4) & 1, ol = t & 15;
    const float* p0 = part + (((((0 << 2) | wo_) << 1) | of_) * 16 + ol) * 4;
    const float* p1 = part + (((((1 << 2) | wo_) << 1) | of_) * 16 + ol) * 4;
    float S = p0[0] + p1[0];
    float Q = p0[1] + p1[1];
    float MX = fmaxf(p0[2], p1[2]);
    float MN = fminf(p0[3], p1[3]);
    int go = (((half << 5) | b) << 10) | (otile << 7) | (wo_ << 5) | (of_ << 4) | ol;
    sum3[go] = S; sq3[go] = Q; maxv[go] = MX; minv[go] = MN;
  }
}

// ---------------- finalize stats3 (+bias fold) + pooled ---------------------------
__global__ void k_fin3_pool(const float* __restrict__ sum3, const float* __restrict__ sq3,
    const float* __restrict__ maxv, const float* __restrict__ minv,
    const float* __restrict__ b3,
    const float* __restrict__ g, const float* __restrict__ be, float* __restrict__ pool) {
  int o = blockIdx.x*256 + threadIdx.x;
  float S = 0.f, Q = 0.f;
  for (int h = 0; h < 2; ++h)
    for (int b = 0; b < 32; ++b) { int gi = (((h<<5)|b)<<10) | o; S += sum3[gi]; Q += sq3[gi]; }
  const float inv = 1.f/131072.f;
  float ma = S*inv;
  float m = ma + b3[o];
  float var = Q*inv - ma*ma;
  float sc = g[o]*rsqrtf(var + EPS);
  float sh = be[o] - sc*m;
  bool pos = (sc >= 0.f);
  for (int b = 0; b < 32; ++b) {
    int g0 = (b << 10) | o, g1 = ((32 + b) << 10) | o;
    float v = pos ? fmaxf(maxv[g0], maxv[g1]) : fminf(minv[g0], minv[g1]);
    pool[(b << 10) | o] = fmaxf(fmaf(sc, v + b3[o], sh), 0.f);
  }
}

// ---------------- fused FC + batch-BN + ReLU --------------------------------------
__global__ __launch_bounds__(256) void k_fc_bn_relu(const float* __restrict__ in,
    const float* __restrict__ w, const float* __restrict__ fb,
    const float* __restrict__ g, const float* __restrict__ be,
    float* __restrict__ out, int K, int F) {
  __shared__ float wrow[1024];
  __shared__ float preb[32];
  int o = blockIdx.x, t = threadIdx.x;
  for (int k = t; k < K; k += 256) wrow[k] = w[(size_t)o*K + k];
  __syncthreads();
  int b = t >> 3, j = t & 7;
  int per = K >> 3;
  const float* inb = in + (size_t)b*K + j*per;
  const float* wp  = wrow + j*per;
  float p = 0.f;
  for (int k = 0; k < per; ++k) p = fmaf(inb[k], wp[k], p);
  p += __shfl_xor(p, 1); p += __shfl_xor(p, 2); p += __shfl_xor(p, 4);
  if (j == 0) preb[b] = p + fb[o];
  __syncthreads();
  if (t < 32) {
    float v = preb[t];
    float s = v;
    #pragma unroll
    for (int d = 1; d < 32; d <<= 1) s += __shfl_xor(s, d);
    float m = s * 0.03125f;
    float dv = v - m;
    float q = dv*dv;
    #pragma unroll
    for (int d = 1; d < 32; d <<= 1) q += __shfl_xor(q, d);
    float var = q * 0.03125f;
    float sc = g[o]*rsqrtf(var + EPS);
    out[(size_t)t*F + o] = fmaxf(fmaf(sc, dv, be[o]), 0.f);
  }
}

// ---------------- angles + Euler->rotation ----------------------------------------
__global__ __launch_bounds__(128) void k_final(const float* __restrict__ h6,
    const float* __restrict__ fw4, const float* __restrict__ fb4, float* __restrict__ out) {
  __shared__ float angs[32][3];
  int t = threadIdx.x;
  if (t < 96) {
    int b = t / 3, j = t % 3;
    float p = 0.f;
    #pragma unroll 4
    for (int k = 0; k < 128; ++k) p = fmaf(h6[b*128+k], fw4[j*128+k], p);
    angs[b][j] = (p + fb4[j]) * PI_F;
  }
  __syncthreads();
  if (t < 32) {
    float a = angs[t][0], bb = angs[t][1], c = angs[t][2];
    float sa, ca; sincosf(a,  &sa, &ca);
    float sb, cb; sincosf(bb, &sb, &cb);
    float sc, cc; sincosf(c,  &sc, &cc);
    float* o9 = out + t*9;
    o9[0] = cc*cb;
    o9[1] = fmaf(cc*sb, sa, -sc*ca);
    o9[2] = fmaf(cc*sb, ca,  sc*sa);
    o9[3] = sc*cb;
    o9[4] = fmaf(sc*sb, sa,  cc*ca);
    o9[5] = fmaf(sc*sb, ca, -cc*sa);
    o9[6] = -sb;
    o9[7] = cb*sa;
    o9[8] = cb*ca;
  }
}

extern "C" void kernel_launch(void* const* d_in, const int* in_sizes, int n_in,
                              void* d_out, int out_size, void* d_ws, size_t ws_size,
                              hipStream_t stream) {
  (void)in_sizes; (void)n_in; (void)out_size; (void)ws_size;
  const float* x   = (const float*)d_in[0];
  const float* w1  = (const float*)d_in[1];
  const float* b1  = (const float*)d_in[2];
  const float* g1  = (const float*)d_in[3];
  const float* be1 = (const float*)d_in[4];
  const float* w2  = (const float*)d_in[5];
  const float* b2  = (const float*)d_in[6];
  const float* g2  = (const float*)d_in[7];
  const float* be2 = (const float*)d_in[8];
  const float* w3  = (const float*)d_in[9];
  const float* b3  = (const float*)d_in[10];
  const float* g3  = (const float*)d_in[11];
  const float* be3 = (const float*)d_in[12];
  const float* fw1 = (const float*)d_in[13];
  const float* fb1 = (const float*)d_in[14];
  const float* g4  = (const float*)d_in[15];
  const float* be4 = (const float*)d_in[16];
  const float* fw2 = (const float*)d_in[17];
  const float* fb2 = (const float*)d_in[18];
  const float* g5p = (const float*)d_in[19];
  const float* be5 = (const float*)d_in[20];
  const float* fw3 = (const float*)d_in[21];
  const float* fb3 = (const float*)d_in[22];
  const float* g6  = (const float*)d_in[23];
  const float* be6 = (const float*)d_in[24];
  const float* fw4 = (const float*)d_in[25];
  const float* fb4 = (const float*)d_in[26];

  u16* h2t_hi = (u16*)d_ws;                     // 32 MiB (frag-major)
  u16* h2t_lo = (u16*)d_ws + 16777216;          // 32 MiB
  float* gram_part = (float*)d_ws;              // 8 MiB, aliases h2t (pre-kE2 only)
  float* acc0 = (float*)d_ws + 16777216;
  float* xst  = acc0;                           // 16
  float* m1v  = acc0 + 16;                      // 64
  float* gram = acc0 + 80;                      // 4096
  float* w1f  = acc0 + 4176;                    // 192
  float* b1f  = acc0 + 4368;                    // 64
  float* w2f  = acc0 + 4432;                    // 8192
  float* b2f  = acc0 + 12624;                   // 128
  float* sum3 = acc0 + 12752;                   // 2*32*1024
  float* sq3  = acc0 + 78288;
  float* maxv = acc0 + 143824;
  float* minv = acc0 + 209360;
  float* pool = acc0 + 274896;                  // 32768
  float* h4v  = acc0 + 307664;                  // 16384
  float* h5v  = acc0 + 324048;                  // 8192
  float* h6v  = acc0 + 332240;                  // 4096

  hipMemsetAsync(acc0, 0, 80ull*4, stream);     // xst + m1v

  kA_xstats<<<128, 256, 0, stream>>>(x, xst);
  kB_fold1<<<1, 64, 0, stream>>>(xst, w1, b1, g1, be1, w1f, b1f);
  kC_gram<<<512, 256, 0, stream>>>(x, w1f, b1f, gram_part, m1v);
  kR_gramred<<<16, 256, 0, stream>>>(gram_part, gram);
  kD_fold2<<<128, 64, 0, stream>>>(gram, m1v, w2, b2, g2, be2, w2f, b2f);
  kE2_layer2<<<512, 256, 0, stream>>>(x, w1f, b1f, w2f, b2f, h2t_hi, h2t_lo);
  k5_layer3<<<512, 512, 0, stream>>>(h2t_hi, h2t_lo, w3, sum3, sq3, maxv, minv);
  k_fin3_pool<<<4, 256, 0, stream>>>(sum3, sq3, maxv, minv, b3, g3, be3, pool);
  k_fc_bn_relu<<<512, 256, 0, stream>>>(pool, fw1, fb1, g4, be4, h4v, 1024, 512);
  k_fc_bn_relu<<<256, 256, 0, stream>>>(h4v, fw2, fb2, g5p, be5, h5v, 512, 256);
  k_fc_bn_relu<<<128, 256, 0, stream>>>(h5v, fw3, fb3, g6, be6, h6v, 256, 128);
  k_final<<<1, 128, 0, stream>>>(h6v, fw4, fb4, (float*)d_out);
}